// Round 8
// baseline (303.499 us; speedup 1.0000x reference)
//
#include <hip/hip_runtime.h>

// GraphSAGE 2-layer: CSR gather-mean (bf16) + bf16 MFMA fused GEMMs.
// R8: GEMM K-loop double-buffered (2-phase prefetch: stage next tile before
//     computing current; one vmcnt(0)+barrier per iter instead of two).
// Keeps R6/R7: zero_kernel, separate cursor, vmcnt fence, gather ILP=4.

constexpr int NN   = 100000;
constexpr int NE   = 625000;
constexpr int DIN  = 128;
constexpr int DHID = 256;
constexpr int NB   = (NN + 255) / 256;     // 391 scan chunks
constexpr int CONV_BLKS = NN * DIN / 8 / 256;   // 6250 (exact)

using short8 = __attribute__((ext_vector_type(8))) short;
using f32x4  = __attribute__((ext_vector_type(4))) float;

__device__ __forceinline__ float bf2f(unsigned int u) {
    return __uint_as_float(u << 16);
}
__device__ __forceinline__ unsigned short f2b(float f) {
    unsigned int u = __float_as_uint(f);
    unsigned int r = (u + 0x7fffu + ((u >> 16) & 1u)) >> 16;   // RNE
    return (unsigned short)r;
}
__device__ __forceinline__ unsigned int pack2(float lo, float hi) {
    return (unsigned int)f2b(lo) | ((unsigned int)f2b(hi) << 16);
}
__device__ __forceinline__ void gload16(const void* g, void* lds) {
    __builtin_amdgcn_global_load_lds(
        (const __attribute__((address_space(1))) void*)g,
        (__attribute__((address_space(3))) void*)lds, 16, 0, 0);
}

// ---------------- CSR build ------------------------------------------------
__global__ __launch_bounds__(256) void zero_kernel(int* __restrict__ p, int n)
{
    int t = blockIdx.x * 256 + threadIdx.x;
    if (t < n) p[t] = 0;
}

__global__ __launch_bounds__(256) void hist_kernel(const int* __restrict__ dst,
                                                   int* __restrict__ hist)
{
    int t = blockIdx.x * 256 + threadIdx.x;
    if (t < NE) atomicAdd(&hist[dst[t]], 1);
}

__global__ __launch_bounds__(256) void chunk_sum_kernel(const int* __restrict__ hist,
                                                        int* __restrict__ bsum)
{
    __shared__ int s[256];
    int i = blockIdx.x * 256 + threadIdx.x;
    s[threadIdx.x] = (i < NN) ? hist[i] : 0;
    __syncthreads();
    for (int off = 128; off > 0; off >>= 1) {
        if (threadIdx.x < off) s[threadIdx.x] += s[threadIdx.x + off];
        __syncthreads();
    }
    if (threadIdx.x == 0) bsum[blockIdx.x] = s[0];
}

__global__ __launch_bounds__(512) void scan_bsum_kernel(const int* __restrict__ bsum,
                                                        int* __restrict__ bpre)
{
    __shared__ int s[512];
    int t = threadIdx.x;
    int v = (t < NB) ? bsum[t] : 0;
    s[t] = v;
    __syncthreads();
    for (int off = 1; off < 512; off <<= 1) {
        int u = (t >= off) ? s[t - off] : 0;
        __syncthreads();
        s[t] += u;
        __syncthreads();
    }
    if (t < NB) bpre[t] = s[t] - v;        // exclusive prefix
}

__global__ __launch_bounds__(256) void scatter_offs_kernel(const int* __restrict__ hist,
                                                           const int* __restrict__ bpre,
                                                           int* __restrict__ offs,
                                                           int* __restrict__ cursor)
{
    __shared__ int s[256];
    int t = threadIdx.x;
    int i = blockIdx.x * 256 + t;
    int v = (i < NN) ? hist[i] : 0;
    s[t] = v;
    __syncthreads();
    for (int off = 1; off < 256; off <<= 1) {
        int u = (t >= off) ? s[t - off] : 0;
        __syncthreads();
        s[t] += u;
        __syncthreads();
    }
    int excl = s[t] - v + bpre[blockIdx.x];
    if (i < NN) {
        offs[i]   = excl;
        cursor[i] = excl;
    }
    if (i == NN - 1) offs[NN] = NE;
}

__global__ __launch_bounds__(256) void perm_kernel(const int* __restrict__ src,
                                                   const int* __restrict__ dst,
                                                   int* __restrict__ cursor,
                                                   int* __restrict__ perm)
{
    int t = blockIdx.x * 256 + threadIdx.x;
    if (t < NE) {
        int p = atomicAdd(&cursor[dst[t]], 1);
        perm[p] = src[t];
    }
}

// ---------------- merged prep: x->bf16, WT0, WT1 ---------------------------
__global__ __launch_bounds__(256) void prep_all_kernel(
    const float* __restrict__ x, unsigned short* __restrict__ xb,
    const float* __restrict__ Wl0, const float* __restrict__ Wr0,
    unsigned short* __restrict__ WT0,
    const float* __restrict__ Wl1, const float* __restrict__ Wr1,
    unsigned short* __restrict__ WT1)
{
    int b = blockIdx.x;
    if (b < CONV_BLKS) {
        int t = b * 256 + threadIdx.x;          // [0, 1.6M) exact
        float4 v0 = reinterpret_cast<const float4*>(x)[t * 2 + 0];
        float4 v1 = reinterpret_cast<const float4*>(x)[t * 2 + 1];
        uint4 o;
        o.x = pack2(v0.x, v0.y); o.y = pack2(v0.z, v0.w);
        o.z = pack2(v1.x, v1.y); o.w = pack2(v1.z, v1.w);
        reinterpret_cast<uint4*>(xb)[t] = o;
    } else if (b < CONV_BLKS + 256) {
        int t = (b - CONV_BLKS) * 256 + threadIdx.x;   // [0, 65536)
        int n = t >> 8, k = t & 255;
        float v = (k < DIN) ? Wl0[(size_t)k * DHID + n]
                            : Wr0[(size_t)(k - DIN) * DHID + n];
        WT0[t] = f2b(v);
    } else {
        int t = (b - CONV_BLKS - 256) * 256 + threadIdx.x;   // [0, 131072)
        int n = t >> 9, k = t & 511;
        float v = (k < DHID) ? Wl1[(size_t)k * DHID + n]
                             : Wr1[(size_t)(k - DHID) * DHID + n];
        WT1[t] = f2b(v);
    }
}

// ---------------- gather-mean aggregation (latency-optimized) --------------
template <int D>
__global__ __launch_bounds__(256) void gather_mean_kernel(
    const int* __restrict__ offs, const int* __restrict__ perm,
    const unsigned short* __restrict__ feat, unsigned short* __restrict__ agg)
{
    const int w    = (blockIdx.x * 256 + threadIdx.x) >> 6;
    const int lane = threadIdx.x & 63;
    if (w >= NN) return;
    const int beg = offs[w], end = offs[w + 1];
    const int deg = end - beg;
    const float sc = 1.0f / (float)(deg > 1 ? deg : 1);

    if constexpr (D == 256) {
        const uint2* base = reinterpret_cast<const uint2*>(feat);
        float a0[4] = {}, a1[4] = {}, a2[4] = {}, a3[4] = {};
        for (int e0 = 0; e0 < deg; e0 += 64) {
            const int chunk = min(deg - e0, 64);
            int pv = (lane < chunk) ? perm[beg + e0 + lane] : 0;
            int i = chunk & 3;
            if (i > 0) {
                int s = __builtin_amdgcn_readlane(pv, 0);
                uint2 v = base[(size_t)s * 64 + lane];
                a1[0] += bf2f(v.x & 0xffffu); a1[1] += bf2f(v.x >> 16);
                a1[2] += bf2f(v.y & 0xffffu); a1[3] += bf2f(v.y >> 16);
            }
            if (i > 1) {
                int s = __builtin_amdgcn_readlane(pv, 1);
                uint2 v = base[(size_t)s * 64 + lane];
                a2[0] += bf2f(v.x & 0xffffu); a2[1] += bf2f(v.x >> 16);
                a2[2] += bf2f(v.y & 0xffffu); a2[3] += bf2f(v.y >> 16);
            }
            if (i > 2) {
                int s = __builtin_amdgcn_readlane(pv, 2);
                uint2 v = base[(size_t)s * 64 + lane];
                a3[0] += bf2f(v.x & 0xffffu); a3[1] += bf2f(v.x >> 16);
                a3[2] += bf2f(v.y & 0xffffu); a3[3] += bf2f(v.y >> 16);
            }
            for (; i + 4 <= chunk; i += 4) {
                int s0 = __builtin_amdgcn_readlane(pv, i + 0);
                int s1 = __builtin_amdgcn_readlane(pv, i + 1);
                int s2 = __builtin_amdgcn_readlane(pv, i + 2);
                int s3 = __builtin_amdgcn_readlane(pv, i + 3);
                uint2 v0 = base[(size_t)s0 * 64 + lane];
                uint2 v1 = base[(size_t)s1 * 64 + lane];
                uint2 v2 = base[(size_t)s2 * 64 + lane];
                uint2 v3 = base[(size_t)s3 * 64 + lane];
                a0[0] += bf2f(v0.x & 0xffffu); a0[1] += bf2f(v0.x >> 16);
                a0[2] += bf2f(v0.y & 0xffffu); a0[3] += bf2f(v0.y >> 16);
                a1[0] += bf2f(v1.x & 0xffffu); a1[1] += bf2f(v1.x >> 16);
                a1[2] += bf2f(v1.y & 0xffffu); a1[3] += bf2f(v1.y >> 16);
                a2[0] += bf2f(v2.x & 0xffffu); a2[1] += bf2f(v2.x >> 16);
                a2[2] += bf2f(v2.y & 0xffffu); a2[3] += bf2f(v2.y >> 16);
                a3[0] += bf2f(v3.x & 0xffffu); a3[1] += bf2f(v3.x >> 16);
                a3[2] += bf2f(v3.y & 0xffffu); a3[3] += bf2f(v3.y >> 16);
            }
        }
        float r0 = (a0[0] + a1[0]) + (a2[0] + a3[0]);
        float r1 = (a0[1] + a1[1]) + (a2[1] + a3[1]);
        float r2 = (a0[2] + a1[2]) + (a2[2] + a3[2]);
        float r3 = (a0[3] + a1[3]) + (a2[3] + a3[3]);
        uint2 o;
        o.x = pack2(r0 * sc, r1 * sc);
        o.y = pack2(r2 * sc, r3 * sc);
        reinterpret_cast<uint2*>(agg)[(size_t)w * 64 + lane] = o;
    } else {   // D == 128: row = 64 uints (4B/lane)
        const unsigned int* base = reinterpret_cast<const unsigned int*>(feat);
        float a0[2] = {}, a1[2] = {}, a2[2] = {}, a3[2] = {};
        for (int e0 = 0; e0 < deg; e0 += 64) {
            const int chunk = min(deg - e0, 64);
            int pv = (lane < chunk) ? perm[beg + e0 + lane] : 0;
            int i = chunk & 3;
            if (i > 0) {
                int s = __builtin_amdgcn_readlane(pv, 0);
                unsigned int v = base[(size_t)s * 64 + lane];
                a1[0] += bf2f(v & 0xffffu); a1[1] += bf2f(v >> 16);
            }
            if (i > 1) {
                int s = __builtin_amdgcn_readlane(pv, 1);
                unsigned int v = base[(size_t)s * 64 + lane];
                a2[0] += bf2f(v & 0xffffu); a2[1] += bf2f(v >> 16);
            }
            if (i > 2) {
                int s = __builtin_amdgcn_readlane(pv, 2);
                unsigned int v = base[(size_t)s * 64 + lane];
                a3[0] += bf2f(v & 0xffffu); a3[1] += bf2f(v >> 16);
            }
            for (; i + 4 <= chunk; i += 4) {
                int s0 = __builtin_amdgcn_readlane(pv, i + 0);
                int s1 = __builtin_amdgcn_readlane(pv, i + 1);
                int s2 = __builtin_amdgcn_readlane(pv, i + 2);
                int s3 = __builtin_amdgcn_readlane(pv, i + 3);
                unsigned int v0 = base[(size_t)s0 * 64 + lane];
                unsigned int v1 = base[(size_t)s1 * 64 + lane];
                unsigned int v2 = base[(size_t)s2 * 64 + lane];
                unsigned int v3 = base[(size_t)s3 * 64 + lane];
                a0[0] += bf2f(v0 & 0xffffu); a0[1] += bf2f(v0 >> 16);
                a1[0] += bf2f(v1 & 0xffffu); a1[1] += bf2f(v1 >> 16);
                a2[0] += bf2f(v2 & 0xffffu); a2[1] += bf2f(v2 >> 16);
                a3[0] += bf2f(v3 & 0xffffu); a3[1] += bf2f(v3 >> 16);
            }
        }
        float r0 = (a0[0] + a1[0]) + (a2[0] + a3[0]);
        float r1 = (a0[1] + a1[1]) + (a2[1] + a3[1]);
        reinterpret_cast<unsigned int*>(agg)[(size_t)w * 64 + lane] = pack2(r0 * sc, r1 * sc);
    }
}

// ---------------- bf16 MFMA fused SAGE GEMM (double-buffered) --------------
// out[m,c] = relu( [agg | xr][m,:] @ WT^T + bias ),  WT is [256][2KP] bf16.
// 128x128 tile, 4 waves, BK=32, 16x16x32 MFMA, LDS XOR swizzle both sides.
// 2-phase: stage(kt+1) issued BEFORE compute(kt); one vmcnt(0)+barrier/iter.
template <int KP, bool WF, bool WB>
__global__ __launch_bounds__(256) void sage_mfma_gemm(
    const unsigned short* __restrict__ Aagg,  // [M, KP] bf16
    const unsigned short* __restrict__ Axr,   // [M, KP] bf16
    const unsigned short* __restrict__ WT,    // [256, 2KP] bf16
    const float* __restrict__ bias,
    float* __restrict__ outf,                 // used if WF
    unsigned short* __restrict__ outb,        // used if WB
    int M)
{
    __shared__ __align__(16) unsigned short As[2][128 * 32];
    __shared__ __align__(16) unsigned short Bs[2][128 * 32];

    const int t   = threadIdx.x;
    const int l   = t & 63;
    const int wid = t >> 6;
    const int wr  = wid >> 1, wc = wid & 1;
    const int m0  = blockIdx.x * 128;
    const int c0  = blockIdx.y * 128;

    const int rin = l >> 2;                  // row within chunk
    const int p   = l & 3;                   // physical 16B slot in row
    const int csw = p ^ (rin & 3);           // swizzled source chunk
    const int ch0 = wid * 2, ch1 = ch0 + 1;

    int arow0 = m0 + ch0 * 16 + rin; if (arow0 >= M) arow0 = M - 1;
    int arow1 = m0 + ch1 * 16 + rin; if (arow1 >= M) arow1 = M - 1;
    const int brow0 = c0 + ch0 * 16 + rin;
    const int brow1 = c0 + ch1 * 16 + rin;

    constexpr int K2 = 2 * KP;
    constexpr int KT = K2 / 32;

    // stage K-tile kt into LDS buffer `buf` (4 x global_load_lds dwordx4)
    auto stage = [&](int buf, int kt) {
        const int kb = kt * 32;
        const unsigned short* Asrc;
        int kk;
        if (kb < KP) { Asrc = Aagg; kk = kb; }
        else         { Asrc = Axr;  kk = kb - KP; }
        gload16(Asrc + (size_t)arow0 * KP + kk + csw * 8, As[buf] + ch0 * 512);
        gload16(Asrc + (size_t)arow1 * KP + kk + csw * 8, As[buf] + ch1 * 512);
        gload16(WT + (size_t)brow0 * K2 + kb + csw * 8, Bs[buf] + ch0 * 512);
        gload16(WT + (size_t)brow1 * K2 + kb + csw * 8, Bs[buf] + ch1 * 512);
    };

    // fragment-read offsets: row = ...+(l&15), slot = (l>>4) ^ (row&3)
    const int fr  = l & 15;
    const int swz = ((l >> 4) ^ (l & 3)) * 8;           // ushort units
    const int aOff = (wr * 64 + fr) * 32 + swz;
    const int bOff = (wc * 64 + fr) * 32 + swz;

    f32x4 acc[4][4] = {};

    stage(0, 0);
    asm volatile("s_waitcnt vmcnt(0)" ::: "memory");
    __syncthreads();

    #pragma unroll 2
    for (int kt = 0; kt < KT; ++kt) {
        const int cur = kt & 1;
        if (kt + 1 < KT) stage(cur ^ 1, kt + 1);   // prefetch next tile

        const unsigned short* Ard = As[cur] + aOff;
        const unsigned short* Brd = Bs[cur] + bOff;
        short8 af[4], bf[4];
        #pragma unroll
        for (int i = 0; i < 4; ++i)
            af[i] = *reinterpret_cast<const short8*>(Ard + i * 512);
        #pragma unroll
        for (int i = 0; i < 4; ++i)
            bf[i] = *reinterpret_cast<const short8*>(Brd + i * 512);
        #pragma unroll
        for (int i = 0; i < 4; ++i)
            #pragma unroll
            for (int j = 0; j < 4; ++j)
                acc[i][j] = __builtin_amdgcn_mfma_f32_16x16x32_bf16(
                    af[i], bf[j], acc[i][j], 0, 0, 0);

        asm volatile("s_waitcnt vmcnt(0)" ::: "memory");  // next tile landed
        __syncthreads();
    }

    // epilogue: C/D layout col = l&15, row = (l>>4)*4 + reg
    const int rq = (l >> 4) * 4;
    #pragma unroll
    for (int fn = 0; fn < 4; ++fn) {
        const int col = c0 + wc * 64 + fn * 16 + fr;
        const float bb = bias[col];
        #pragma unroll
        for (int fm = 0; fm < 4; ++fm) {
            const int rbase = m0 + wr * 64 + fm * 16 + rq;
            #pragma unroll
            for (int j = 0; j < 4; ++j) {
                const int r = rbase + j;
                if (r < M) {
                    float v = fmaxf(acc[fm][fn][j] + bb, 0.f);
                    if (WF) outf[(size_t)r * DHID + col] = v;
                    if (WB) outb[(size_t)r * DHID + col] = f2b(v);
                }
            }
        }
    }
}

extern "C" void kernel_launch(void* const* d_in, const int* in_sizes, int n_in,
                              void* d_out, int out_size, void* d_ws, size_t ws_size,
                              hipStream_t stream)
{
    const float* x   = (const float*)d_in[0];
    const int*   ei  = (const int*)d_in[1];
    const int*   src = ei;
    const int*   dst = ei + NE;
    const float* Wl0 = (const float*)d_in[2];
    const float* Wr0 = (const float*)d_in[3];
    const float* b0  = (const float*)d_in[4];
    const float* Wl1 = (const float*)d_in[5];
    const float* Wr1 = (const float*)d_in[6];
    const float* b1  = (const float*)d_in[7];
    float* out = (float*)d_out;

    // workspace layout (bytes):
    //   hist    : @0          400384
    //   offs    : @400384     400640
    //   perm    : @801024     2500352
    //   bsum    : @3301376    4096
    //   bpre    : @3305472    4096
    //   cursor  : @3309568    400384
    //   WT0     : @3709952    131072
    //   WT1     : @3841024    262144
    //   xb      : @4103168    25600000
    //   h0b     : @29703168   51200000
    //   aggb    : @80903168   51200000
    // total ~132.1 MB
    char* ws = (char*)d_ws;
    int*            hist   = (int*)(ws);
    int*            offs   = (int*)(ws + 400384);
    int*            perm   = (int*)(ws + 801024);
    int*            bsum   = (int*)(ws + 3301376);
    int*            bpre   = (int*)(ws + 3305472);
    int*            cursor = (int*)(ws + 3309568);
    unsigned short* WT0    = (unsigned short*)(ws + 3709952);
    unsigned short* WT1    = (unsigned short*)(ws + 3841024);
    unsigned short* xb     = (unsigned short*)(ws + 4103168);
    unsigned short* h0b    = (unsigned short*)(ws + 29703168);
    unsigned short* aggb   = (unsigned short*)(ws + 80903168);

    zero_kernel<<<(NN + 255) / 256, 256, 0, stream>>>(hist, NN);
    hist_kernel<<<(NE + 255) / 256, 256, 0, stream>>>(dst, hist);
    chunk_sum_kernel<<<NB, 256, 0, stream>>>(hist, bsum);
    scan_bsum_kernel<<<1, 512, 0, stream>>>(bsum, bpre);
    scatter_offs_kernel<<<NB, 256, 0, stream>>>(hist, bpre, offs, cursor);
    perm_kernel<<<(NE + 255) / 256, 256, 0, stream>>>(src, dst, cursor, perm);

    prep_all_kernel<<<CONV_BLKS + 256 + 512, 256, 0, stream>>>(
        x, xb, Wl0, Wr0, WT0, Wl1, Wr1, WT1);

    constexpr int NWBLK = (NN * 64) / 256;   // 25000 exactly
    dim3 ggrid((NN + 127) / 128, DHID / 128);

    // ---- layer 0 ----
    gather_mean_kernel<DIN><<<NWBLK, 256, 0, stream>>>(offs, perm, xb, aggb);
    sage_mfma_gemm<DIN, false, true><<<ggrid, 256, 0, stream>>>(
        aggb, xb, WT0, b0, nullptr, h0b, NN);

    // ---- layer 1 ----
    gather_mean_kernel<DHID><<<NWBLK, 256, 0, stream>>>(offs, perm, h0b, aggb);
    sage_mfma_gemm<DHID, true, false><<<ggrid, 256, 0, stream>>>(
        aggb, h0b, WT1, b1, out, nullptr, NN);
}

// Round 9
// 298.546 us; speedup vs baseline: 1.0166x; 1.0166x over previous
//
#include <hip/hip_runtime.h>

// GraphSAGE 2-layer: CSR gather-mean (bf16) + bf16 MFMA fused GEMMs.
// R9: GEMM pipeline fixed — counted vmcnt(4) + RAW s_barrier (no syncthreads
//     auto-drain); conflict-free LDS swizzle c = hi ^ ((r>>1)&3) (was 4-way).

constexpr int NN   = 100000;
constexpr int NE   = 625000;
constexpr int DIN  = 128;
constexpr int DHID = 256;
constexpr int NB   = (NN + 255) / 256;     // 391 scan chunks
constexpr int CONV_BLKS = NN * DIN / 8 / 256;   // 6250 (exact)

using short8 = __attribute__((ext_vector_type(8))) short;
using f32x4  = __attribute__((ext_vector_type(4))) float;

__device__ __forceinline__ float bf2f(unsigned int u) {
    return __uint_as_float(u << 16);
}
__device__ __forceinline__ unsigned short f2b(float f) {
    unsigned int u = __float_as_uint(f);
    unsigned int r = (u + 0x7fffu + ((u >> 16) & 1u)) >> 16;   // RNE
    return (unsigned short)r;
}
__device__ __forceinline__ unsigned int pack2(float lo, float hi) {
    return (unsigned int)f2b(lo) | ((unsigned int)f2b(hi) << 16);
}
__device__ __forceinline__ void gload16(const void* g, void* lds) {
    __builtin_amdgcn_global_load_lds(
        (const __attribute__((address_space(1))) void*)g,
        (__attribute__((address_space(3))) void*)lds, 16, 0, 0);
}

// ---------------- CSR build ------------------------------------------------
__global__ __launch_bounds__(256) void zero_kernel(int* __restrict__ p, int n)
{
    int t = blockIdx.x * 256 + threadIdx.x;
    if (t < n) p[t] = 0;
}

__global__ __launch_bounds__(256) void hist_kernel(const int* __restrict__ dst,
                                                   int* __restrict__ hist)
{
    int t = blockIdx.x * 256 + threadIdx.x;
    if (t < NE) atomicAdd(&hist[dst[t]], 1);
}

__global__ __launch_bounds__(256) void chunk_sum_kernel(const int* __restrict__ hist,
                                                        int* __restrict__ bsum)
{
    __shared__ int s[256];
    int i = blockIdx.x * 256 + threadIdx.x;
    s[threadIdx.x] = (i < NN) ? hist[i] : 0;
    __syncthreads();
    for (int off = 128; off > 0; off >>= 1) {
        if (threadIdx.x < off) s[threadIdx.x] += s[threadIdx.x + off];
        __syncthreads();
    }
    if (threadIdx.x == 0) bsum[blockIdx.x] = s[0];
}

__global__ __launch_bounds__(512) void scan_bsum_kernel(const int* __restrict__ bsum,
                                                        int* __restrict__ bpre)
{
    __shared__ int s[512];
    int t = threadIdx.x;
    int v = (t < NB) ? bsum[t] : 0;
    s[t] = v;
    __syncthreads();
    for (int off = 1; off < 512; off <<= 1) {
        int u = (t >= off) ? s[t - off] : 0;
        __syncthreads();
        s[t] += u;
        __syncthreads();
    }
    if (t < NB) bpre[t] = s[t] - v;        // exclusive prefix
}

__global__ __launch_bounds__(256) void scatter_offs_kernel(const int* __restrict__ hist,
                                                           const int* __restrict__ bpre,
                                                           int* __restrict__ offs,
                                                           int* __restrict__ cursor)
{
    __shared__ int s[256];
    int t = threadIdx.x;
    int i = blockIdx.x * 256 + t;
    int v = (i < NN) ? hist[i] : 0;
    s[t] = v;
    __syncthreads();
    for (int off = 1; off < 256; off <<= 1) {
        int u = (t >= off) ? s[t - off] : 0;
        __syncthreads();
        s[t] += u;
        __syncthreads();
    }
    int excl = s[t] - v + bpre[blockIdx.x];
    if (i < NN) {
        offs[i]   = excl;
        cursor[i] = excl;
    }
    if (i == NN - 1) offs[NN] = NE;
}

__global__ __launch_bounds__(256) void perm_kernel(const int* __restrict__ src,
                                                   const int* __restrict__ dst,
                                                   int* __restrict__ cursor,
                                                   int* __restrict__ perm)
{
    int t = blockIdx.x * 256 + threadIdx.x;
    if (t < NE) {
        int p = atomicAdd(&cursor[dst[t]], 1);
        perm[p] = src[t];
    }
}

// ---------------- merged prep: x->bf16, WT0, WT1 ---------------------------
__global__ __launch_bounds__(256) void prep_all_kernel(
    const float* __restrict__ x, unsigned short* __restrict__ xb,
    const float* __restrict__ Wl0, const float* __restrict__ Wr0,
    unsigned short* __restrict__ WT0,
    const float* __restrict__ Wl1, const float* __restrict__ Wr1,
    unsigned short* __restrict__ WT1)
{
    int b = blockIdx.x;
    if (b < CONV_BLKS) {
        int t = b * 256 + threadIdx.x;          // [0, 1.6M) exact
        float4 v0 = reinterpret_cast<const float4*>(x)[t * 2 + 0];
        float4 v1 = reinterpret_cast<const float4*>(x)[t * 2 + 1];
        uint4 o;
        o.x = pack2(v0.x, v0.y); o.y = pack2(v0.z, v0.w);
        o.z = pack2(v1.x, v1.y); o.w = pack2(v1.z, v1.w);
        reinterpret_cast<uint4*>(xb)[t] = o;
    } else if (b < CONV_BLKS + 256) {
        int t = (b - CONV_BLKS) * 256 + threadIdx.x;   // [0, 65536)
        int n = t >> 8, k = t & 255;
        float v = (k < DIN) ? Wl0[(size_t)k * DHID + n]
                            : Wr0[(size_t)(k - DIN) * DHID + n];
        WT0[t] = f2b(v);
    } else {
        int t = (b - CONV_BLKS - 256) * 256 + threadIdx.x;   // [0, 131072)
        int n = t >> 9, k = t & 511;
        float v = (k < DHID) ? Wl1[(size_t)k * DHID + n]
                             : Wr1[(size_t)(k - DHID) * DHID + n];
        WT1[t] = f2b(v);
    }
}

// ---------------- gather-mean aggregation (latency-optimized) --------------
template <int D>
__global__ __launch_bounds__(256) void gather_mean_kernel(
    const int* __restrict__ offs, const int* __restrict__ perm,
    const unsigned short* __restrict__ feat, unsigned short* __restrict__ agg)
{
    const int w    = (blockIdx.x * 256 + threadIdx.x) >> 6;
    const int lane = threadIdx.x & 63;
    if (w >= NN) return;
    const int beg = offs[w], end = offs[w + 1];
    const int deg = end - beg;
    const float sc = 1.0f / (float)(deg > 1 ? deg : 1);

    if constexpr (D == 256) {
        const uint2* base = reinterpret_cast<const uint2*>(feat);
        float a0[4] = {}, a1[4] = {}, a2[4] = {}, a3[4] = {};
        for (int e0 = 0; e0 < deg; e0 += 64) {
            const int chunk = min(deg - e0, 64);
            int pv = (lane < chunk) ? perm[beg + e0 + lane] : 0;
            int i = chunk & 3;
            if (i > 0) {
                int s = __builtin_amdgcn_readlane(pv, 0);
                uint2 v = base[(size_t)s * 64 + lane];
                a1[0] += bf2f(v.x & 0xffffu); a1[1] += bf2f(v.x >> 16);
                a1[2] += bf2f(v.y & 0xffffu); a1[3] += bf2f(v.y >> 16);
            }
            if (i > 1) {
                int s = __builtin_amdgcn_readlane(pv, 1);
                uint2 v = base[(size_t)s * 64 + lane];
                a2[0] += bf2f(v.x & 0xffffu); a2[1] += bf2f(v.x >> 16);
                a2[2] += bf2f(v.y & 0xffffu); a2[3] += bf2f(v.y >> 16);
            }
            if (i > 2) {
                int s = __builtin_amdgcn_readlane(pv, 2);
                uint2 v = base[(size_t)s * 64 + lane];
                a3[0] += bf2f(v.x & 0xffffu); a3[1] += bf2f(v.x >> 16);
                a3[2] += bf2f(v.y & 0xffffu); a3[3] += bf2f(v.y >> 16);
            }
            for (; i + 4 <= chunk; i += 4) {
                int s0 = __builtin_amdgcn_readlane(pv, i + 0);
                int s1 = __builtin_amdgcn_readlane(pv, i + 1);
                int s2 = __builtin_amdgcn_readlane(pv, i + 2);
                int s3 = __builtin_amdgcn_readlane(pv, i + 3);
                uint2 v0 = base[(size_t)s0 * 64 + lane];
                uint2 v1 = base[(size_t)s1 * 64 + lane];
                uint2 v2 = base[(size_t)s2 * 64 + lane];
                uint2 v3 = base[(size_t)s3 * 64 + lane];
                a0[0] += bf2f(v0.x & 0xffffu); a0[1] += bf2f(v0.x >> 16);
                a0[2] += bf2f(v0.y & 0xffffu); a0[3] += bf2f(v0.y >> 16);
                a1[0] += bf2f(v1.x & 0xffffu); a1[1] += bf2f(v1.x >> 16);
                a1[2] += bf2f(v1.y & 0xffffu); a1[3] += bf2f(v1.y >> 16);
                a2[0] += bf2f(v2.x & 0xffffu); a2[1] += bf2f(v2.x >> 16);
                a2[2] += bf2f(v2.y & 0xffffu); a2[3] += bf2f(v2.y >> 16);
                a3[0] += bf2f(v3.x & 0xffffu); a3[1] += bf2f(v3.x >> 16);
                a3[2] += bf2f(v3.y & 0xffffu); a3[3] += bf2f(v3.y >> 16);
            }
        }
        float r0 = (a0[0] + a1[0]) + (a2[0] + a3[0]);
        float r1 = (a0[1] + a1[1]) + (a2[1] + a3[1]);
        float r2 = (a0[2] + a1[2]) + (a2[2] + a3[2]);
        float r3 = (a0[3] + a1[3]) + (a2[3] + a3[3]);
        uint2 o;
        o.x = pack2(r0 * sc, r1 * sc);
        o.y = pack2(r2 * sc, r3 * sc);
        reinterpret_cast<uint2*>(agg)[(size_t)w * 64 + lane] = o;
    } else {   // D == 128: row = 64 uints (4B/lane)
        const unsigned int* base = reinterpret_cast<const unsigned int*>(feat);
        float a0[2] = {}, a1[2] = {}, a2[2] = {}, a3[2] = {};
        for (int e0 = 0; e0 < deg; e0 += 64) {
            const int chunk = min(deg - e0, 64);
            int pv = (lane < chunk) ? perm[beg + e0 + lane] : 0;
            int i = chunk & 3;
            if (i > 0) {
                int s = __builtin_amdgcn_readlane(pv, 0);
                unsigned int v = base[(size_t)s * 64 + lane];
                a1[0] += bf2f(v & 0xffffu); a1[1] += bf2f(v >> 16);
            }
            if (i > 1) {
                int s = __builtin_amdgcn_readlane(pv, 1);
                unsigned int v = base[(size_t)s * 64 + lane];
                a2[0] += bf2f(v & 0xffffu); a2[1] += bf2f(v >> 16);
            }
            if (i > 2) {
                int s = __builtin_amdgcn_readlane(pv, 2);
                unsigned int v = base[(size_t)s * 64 + lane];
                a3[0] += bf2f(v & 0xffffu); a3[1] += bf2f(v >> 16);
            }
            for (; i + 4 <= chunk; i += 4) {
                int s0 = __builtin_amdgcn_readlane(pv, i + 0);
                int s1 = __builtin_amdgcn_readlane(pv, i + 1);
                int s2 = __builtin_amdgcn_readlane(pv, i + 2);
                int s3 = __builtin_amdgcn_readlane(pv, i + 3);
                unsigned int v0 = base[(size_t)s0 * 64 + lane];
                unsigned int v1 = base[(size_t)s1 * 64 + lane];
                unsigned int v2 = base[(size_t)s2 * 64 + lane];
                unsigned int v3 = base[(size_t)s3 * 64 + lane];
                a0[0] += bf2f(v0 & 0xffffu); a0[1] += bf2f(v0 >> 16);
                a1[0] += bf2f(v1 & 0xffffu); a1[1] += bf2f(v1 >> 16);
                a2[0] += bf2f(v2 & 0xffffu); a2[1] += bf2f(v2 >> 16);
                a3[0] += bf2f(v3 & 0xffffu); a3[1] += bf2f(v3 >> 16);
            }
        }
        float r0 = (a0[0] + a1[0]) + (a2[0] + a3[0]);
        float r1 = (a0[1] + a1[1]) + (a2[1] + a3[1]);
        reinterpret_cast<unsigned int*>(agg)[(size_t)w * 64 + lane] = pack2(r0 * sc, r1 * sc);
    }
}

// ---------------- bf16 MFMA fused SAGE GEMM (counted-vmcnt pipeline) -------
// out[m,c] = relu( [agg | xr][m,:] @ WT^T + bias ),  WT is [256][2KP] bf16.
// 128x128 tile, 4 waves, BK=32, 16x16x32 MFMA.
// LDS (rc, chunk c) holds global chunk g = c ^ s(rc), s(rc) = (rc>>1)&3:
// conflict-free (bank quads walk {0,4,1,5,2,6,3,7}, uniform 2-way).
// Pipeline: stage(kt+1) -> vmcnt(4) (tile kt landed, kt+1 in flight) ->
// raw s_barrier -> ds_read+MFMA -> lgkmcnt(0) -> raw s_barrier.
template <int KP, bool WF, bool WB>
__global__ __launch_bounds__(256) void sage_mfma_gemm(
    const unsigned short* __restrict__ Aagg,  // [M, KP] bf16
    const unsigned short* __restrict__ Axr,   // [M, KP] bf16
    const unsigned short* __restrict__ WT,    // [256, 2KP] bf16
    const float* __restrict__ bias,
    float* __restrict__ outf,                 // used if WF
    unsigned short* __restrict__ outb,        // used if WB
    int M)
{
    __shared__ __align__(16) unsigned short As[2][128 * 32];
    __shared__ __align__(16) unsigned short Bs[2][128 * 32];

    const int t   = threadIdx.x;
    const int l   = t & 63;
    const int wid = t >> 6;
    const int wr  = wid >> 1, wc = wid & 1;
    const int m0  = blockIdx.x * 128;
    const int c0  = blockIdx.y * 128;

    // staging coords: lane l writes LDS (rc = l>>2, c = l&3) of its chunk;
    // source must be global chunk g = c ^ s(rc) = (l&3) ^ ((l>>3)&3)
    const int rin = l >> 2;
    const int csw = (l & 3) ^ ((l >> 3) & 3);
    const int ch0 = wid * 2, ch1 = ch0 + 1;

    int arow0 = m0 + ch0 * 16 + rin; if (arow0 >= M) arow0 = M - 1;
    int arow1 = m0 + ch1 * 16 + rin; if (arow1 >= M) arow1 = M - 1;
    const int brow0 = c0 + ch0 * 16 + rin;
    const int brow1 = c0 + ch1 * 16 + rin;

    constexpr int K2 = 2 * KP;
    constexpr int KT = K2 / 32;

    auto stage = [&](int buf, int kt) {
        const int kb = kt * 32;
        const unsigned short* Asrc;
        int kk;
        if (kb < KP) { Asrc = Aagg; kk = kb; }
        else         { Asrc = Axr;  kk = kb - KP; }
        gload16(Asrc + (size_t)arow0 * KP + kk + csw * 8, As[buf] + ch0 * 512);
        gload16(Asrc + (size_t)arow1 * KP + kk + csw * 8, As[buf] + ch1 * 512);
        gload16(WT + (size_t)brow0 * K2 + kb + csw * 8, Bs[buf] + ch0 * 512);
        gload16(WT + (size_t)brow1 * K2 + kb + csw * 8, Bs[buf] + ch1 * 512);
    };

    // read coords: row rc = l&15, logical chunk g = l>>4,
    // lds chunk = g ^ s(rc) = (l>>4) ^ ((l>>1)&3)
    const int fr  = l & 15;
    const int swz = ((l >> 4) ^ ((l >> 1) & 3)) * 8;    // ushort units
    const int aOff = (wr * 64 + fr) * 32 + swz;
    const int bOff = (wc * 64 + fr) * 32 + swz;

    f32x4 acc[4][4] = {};

    stage(0, 0);

    #pragma unroll 2
    for (int kt = 0; kt < KT; ++kt) {
        const int cur = kt & 1;
        if (kt + 1 < KT) {
            stage(cur ^ 1, kt + 1);   // prefetch next tile (4 loads in flight)
            asm volatile("s_waitcnt vmcnt(4)" ::: "memory");   // tile kt landed
        } else {
            asm volatile("s_waitcnt vmcnt(0)" ::: "memory");
        }
        __builtin_amdgcn_s_barrier();            // raw: no auto vmcnt(0) drain
        __builtin_amdgcn_sched_barrier(0);

        const unsigned short* Ard = As[cur] + aOff;
        const unsigned short* Brd = Bs[cur] + bOff;
        short8 af[4], bf[4];
        #pragma unroll
        for (int i = 0; i < 4; ++i)
            af[i] = *reinterpret_cast<const short8*>(Ard + i * 512);
        #pragma unroll
        for (int i = 0; i < 4; ++i)
            bf[i] = *reinterpret_cast<const short8*>(Brd + i * 512);
        #pragma unroll
        for (int i = 0; i < 4; ++i)
            #pragma unroll
            for (int j = 0; j < 4; ++j)
                acc[i][j] = __builtin_amdgcn_mfma_f32_16x16x32_bf16(
                    af[i], bf[j], acc[i][j], 0, 0, 0);

        asm volatile("s_waitcnt lgkmcnt(0)" ::: "memory");  // reads done
        __builtin_amdgcn_s_barrier();            // safe to overwrite buf cur
        __builtin_amdgcn_sched_barrier(0);
    }

    // epilogue: C/D layout col = l&15, row = (l>>4)*4 + reg
    const int rq = (l >> 4) * 4;
    #pragma unroll
    for (int fn = 0; fn < 4; ++fn) {
        const int col = c0 + wc * 64 + fn * 16 + fr;
        const float bb = bias[col];
        #pragma unroll
        for (int fm = 0; fm < 4; ++fm) {
            const int rbase = m0 + wr * 64 + fm * 16 + rq;
            #pragma unroll
            for (int j = 0; j < 4; ++j) {
                const int r = rbase + j;
                if (r < M) {
                    float v = fmaxf(acc[fm][fn][j] + bb, 0.f);
                    if (WF) outf[(size_t)r * DHID + col] = v;
                    if (WB) outb[(size_t)r * DHID + col] = f2b(v);
                }
            }
        }
    }
}

extern "C" void kernel_launch(void* const* d_in, const int* in_sizes, int n_in,
                              void* d_out, int out_size, void* d_ws, size_t ws_size,
                              hipStream_t stream)
{
    const float* x   = (const float*)d_in[0];
    const int*   ei  = (const int*)d_in[1];
    const int*   src = ei;
    const int*   dst = ei + NE;
    const float* Wl0 = (const float*)d_in[2];
    const float* Wr0 = (const float*)d_in[3];
    const float* b0  = (const float*)d_in[4];
    const float* Wl1 = (const float*)d_in[5];
    const float* Wr1 = (const float*)d_in[6];
    const float* b1  = (const float*)d_in[7];
    float* out = (float*)d_out;

    // workspace layout (bytes):
    //   hist    : @0          400384
    //   offs    : @400384     400640
    //   perm    : @801024     2500352
    //   bsum    : @3301376    4096
    //   bpre    : @3305472    4096
    //   cursor  : @3309568    400384
    //   WT0     : @3709952    131072
    //   WT1     : @3841024    262144
    //   xb      : @4103168    25600000
    //   h0b     : @29703168   51200000
    //   aggb    : @80903168   51200000
    // total ~132.1 MB
    char* ws = (char*)d_ws;
    int*            hist   = (int*)(ws);
    int*            offs   = (int*)(ws + 400384);
    int*            perm   = (int*)(ws + 801024);
    int*            bsum   = (int*)(ws + 3301376);
    int*            bpre   = (int*)(ws + 3305472);
    int*            cursor = (int*)(ws + 3309568);
    unsigned short* WT0    = (unsigned short*)(ws + 3709952);
    unsigned short* WT1    = (unsigned short*)(ws + 3841024);
    unsigned short* xb     = (unsigned short*)(ws + 4103168);
    unsigned short* h0b    = (unsigned short*)(ws + 29703168);
    unsigned short* aggb   = (unsigned short*)(ws + 80903168);

    zero_kernel<<<(NN + 255) / 256, 256, 0, stream>>>(hist, NN);
    hist_kernel<<<(NE + 255) / 256, 256, 0, stream>>>(dst, hist);
    chunk_sum_kernel<<<NB, 256, 0, stream>>>(hist, bsum);
    scan_bsum_kernel<<<1, 512, 0, stream>>>(bsum, bpre);
    scatter_offs_kernel<<<NB, 256, 0, stream>>>(hist, bpre, offs, cursor);
    perm_kernel<<<(NE + 255) / 256, 256, 0, stream>>>(src, dst, cursor, perm);

    prep_all_kernel<<<CONV_BLKS + 256 + 512, 256, 0, stream>>>(
        x, xb, Wl0, Wr0, WT0, Wl1, Wr1, WT1);

    constexpr int NWBLK = (NN * 64) / 256;   // 25000 exactly
    dim3 ggrid((NN + 127) / 128, DHID / 128);

    // ---- layer 0 ----
    gather_mean_kernel<DIN><<<NWBLK, 256, 0, stream>>>(offs, perm, xb, aggb);
    sage_mfma_gemm<DIN, false, true><<<ggrid, 256, 0, stream>>>(
        aggb, xb, WT0, b0, nullptr, h0b, NN);

    // ---- layer 1 ----
    gather_mean_kernel<DHID><<<NWBLK, 256, 0, stream>>>(offs, perm, h0b, aggb);
    sage_mfma_gemm<DHID, true, false><<<ggrid, 256, 0, stream>>>(
        aggb, h0b, WT1, b1, out, nullptr, NN);
}

// Round 10
// 273.724 us; speedup vs baseline: 1.1088x; 1.0907x over previous
//
#include <hip/hip_runtime.h>

// GraphSAGE 2-layer: CSR gather-mean (bf16) + bf16 MFMA fused GEMMs.
// R10: GEMM restructured for concurrency: 128x256 tile (full N), 512 thr
//      (8 waves 2x4), 3-buffer BK=32, 2-deep prefetch, vmcnt(6) steady.
//      A read once (grid.y gone). Per-wave math identical to R9 (verified).

constexpr int NN   = 100000;
constexpr int NE   = 625000;
constexpr int DIN  = 128;
constexpr int DHID = 256;
constexpr int NB   = (NN + 255) / 256;     // 391 scan chunks
constexpr int CONV_BLKS = NN * DIN / 8 / 256;   // 6250 (exact)

using short8 = __attribute__((ext_vector_type(8))) short;
using f32x4  = __attribute__((ext_vector_type(4))) float;

__device__ __forceinline__ float bf2f(unsigned int u) {
    return __uint_as_float(u << 16);
}
__device__ __forceinline__ unsigned short f2b(float f) {
    unsigned int u = __float_as_uint(f);
    unsigned int r = (u + 0x7fffu + ((u >> 16) & 1u)) >> 16;   // RNE
    return (unsigned short)r;
}
__device__ __forceinline__ unsigned int pack2(float lo, float hi) {
    return (unsigned int)f2b(lo) | ((unsigned int)f2b(hi) << 16);
}
__device__ __forceinline__ void gload16(const void* g, void* lds) {
    __builtin_amdgcn_global_load_lds(
        (const __attribute__((address_space(1))) void*)g,
        (__attribute__((address_space(3))) void*)lds, 16, 0, 0);
}

// ---------------- CSR build ------------------------------------------------
__global__ __launch_bounds__(256) void zero_kernel(int* __restrict__ p, int n)
{
    int t = blockIdx.x * 256 + threadIdx.x;
    if (t < n) p[t] = 0;
}

__global__ __launch_bounds__(256) void hist_kernel(const int* __restrict__ dst,
                                                   int* __restrict__ hist)
{
    int t = blockIdx.x * 256 + threadIdx.x;
    if (t < NE) atomicAdd(&hist[dst[t]], 1);
}

__global__ __launch_bounds__(256) void chunk_sum_kernel(const int* __restrict__ hist,
                                                        int* __restrict__ bsum)
{
    __shared__ int s[256];
    int i = blockIdx.x * 256 + threadIdx.x;
    s[threadIdx.x] = (i < NN) ? hist[i] : 0;
    __syncthreads();
    for (int off = 128; off > 0; off >>= 1) {
        if (threadIdx.x < off) s[threadIdx.x] += s[threadIdx.x + off];
        __syncthreads();
    }
    if (threadIdx.x == 0) bsum[blockIdx.x] = s[0];
}

__global__ __launch_bounds__(512) void scan_bsum_kernel(const int* __restrict__ bsum,
                                                        int* __restrict__ bpre)
{
    __shared__ int s[512];
    int t = threadIdx.x;
    int v = (t < NB) ? bsum[t] : 0;
    s[t] = v;
    __syncthreads();
    for (int off = 1; off < 512; off <<= 1) {
        int u = (t >= off) ? s[t - off] : 0;
        __syncthreads();
        s[t] += u;
        __syncthreads();
    }
    if (t < NB) bpre[t] = s[t] - v;        // exclusive prefix
}

__global__ __launch_bounds__(256) void scatter_offs_kernel(const int* __restrict__ hist,
                                                           const int* __restrict__ bpre,
                                                           int* __restrict__ offs,
                                                           int* __restrict__ cursor)
{
    __shared__ int s[256];
    int t = threadIdx.x;
    int i = blockIdx.x * 256 + t;
    int v = (i < NN) ? hist[i] : 0;
    s[t] = v;
    __syncthreads();
    for (int off = 1; off < 256; off <<= 1) {
        int u = (t >= off) ? s[t - off] : 0;
        __syncthreads();
        s[t] += u;
        __syncthreads();
    }
    int excl = s[t] - v + bpre[blockIdx.x];
    if (i < NN) {
        offs[i]   = excl;
        cursor[i] = excl;
    }
    if (i == NN - 1) offs[NN] = NE;
}

__global__ __launch_bounds__(256) void perm_kernel(const int* __restrict__ src,
                                                   const int* __restrict__ dst,
                                                   int* __restrict__ cursor,
                                                   int* __restrict__ perm)
{
    int t = blockIdx.x * 256 + threadIdx.x;
    if (t < NE) {
        int p = atomicAdd(&cursor[dst[t]], 1);
        perm[p] = src[t];
    }
}

// ---------------- merged prep: x->bf16, WT0, WT1 ---------------------------
__global__ __launch_bounds__(256) void prep_all_kernel(
    const float* __restrict__ x, unsigned short* __restrict__ xb,
    const float* __restrict__ Wl0, const float* __restrict__ Wr0,
    unsigned short* __restrict__ WT0,
    const float* __restrict__ Wl1, const float* __restrict__ Wr1,
    unsigned short* __restrict__ WT1)
{
    int b = blockIdx.x;
    if (b < CONV_BLKS) {
        int t = b * 256 + threadIdx.x;          // [0, 1.6M) exact
        float4 v0 = reinterpret_cast<const float4*>(x)[t * 2 + 0];
        float4 v1 = reinterpret_cast<const float4*>(x)[t * 2 + 1];
        uint4 o;
        o.x = pack2(v0.x, v0.y); o.y = pack2(v0.z, v0.w);
        o.z = pack2(v1.x, v1.y); o.w = pack2(v1.z, v1.w);
        reinterpret_cast<uint4*>(xb)[t] = o;
    } else if (b < CONV_BLKS + 256) {
        int t = (b - CONV_BLKS) * 256 + threadIdx.x;   // [0, 65536)
        int n = t >> 8, k = t & 255;
        float v = (k < DIN) ? Wl0[(size_t)k * DHID + n]
                            : Wr0[(size_t)(k - DIN) * DHID + n];
        WT0[t] = f2b(v);
    } else {
        int t = (b - CONV_BLKS - 256) * 256 + threadIdx.x;   // [0, 131072)
        int n = t >> 9, k = t & 511;
        float v = (k < DHID) ? Wl1[(size_t)k * DHID + n]
                             : Wr1[(size_t)(k - DHID) * DHID + n];
        WT1[t] = f2b(v);
    }
}

// ---------------- gather-mean aggregation (latency-optimized) --------------
template <int D>
__global__ __launch_bounds__(256) void gather_mean_kernel(
    const int* __restrict__ offs, const int* __restrict__ perm,
    const unsigned short* __restrict__ feat, unsigned short* __restrict__ agg)
{
    const int w    = (blockIdx.x * 256 + threadIdx.x) >> 6;
    const int lane = threadIdx.x & 63;
    if (w >= NN) return;
    const int beg = offs[w], end = offs[w + 1];
    const int deg = end - beg;
    const float sc = 1.0f / (float)(deg > 1 ? deg : 1);

    if constexpr (D == 256) {
        const uint2* base = reinterpret_cast<const uint2*>(feat);
        float a0[4] = {}, a1[4] = {}, a2[4] = {}, a3[4] = {};
        for (int e0 = 0; e0 < deg; e0 += 64) {
            const int chunk = min(deg - e0, 64);
            int pv = (lane < chunk) ? perm[beg + e0 + lane] : 0;
            int i = chunk & 3;
            if (i > 0) {
                int s = __builtin_amdgcn_readlane(pv, 0);
                uint2 v = base[(size_t)s * 64 + lane];
                a1[0] += bf2f(v.x & 0xffffu); a1[1] += bf2f(v.x >> 16);
                a1[2] += bf2f(v.y & 0xffffu); a1[3] += bf2f(v.y >> 16);
            }
            if (i > 1) {
                int s = __builtin_amdgcn_readlane(pv, 1);
                uint2 v = base[(size_t)s * 64 + lane];
                a2[0] += bf2f(v.x & 0xffffu); a2[1] += bf2f(v.x >> 16);
                a2[2] += bf2f(v.y & 0xffffu); a2[3] += bf2f(v.y >> 16);
            }
            if (i > 2) {
                int s = __builtin_amdgcn_readlane(pv, 2);
                uint2 v = base[(size_t)s * 64 + lane];
                a3[0] += bf2f(v.x & 0xffffu); a3[1] += bf2f(v.x >> 16);
                a3[2] += bf2f(v.y & 0xffffu); a3[3] += bf2f(v.y >> 16);
            }
            for (; i + 4 <= chunk; i += 4) {
                int s0 = __builtin_amdgcn_readlane(pv, i + 0);
                int s1 = __builtin_amdgcn_readlane(pv, i + 1);
                int s2 = __builtin_amdgcn_readlane(pv, i + 2);
                int s3 = __builtin_amdgcn_readlane(pv, i + 3);
                uint2 v0 = base[(size_t)s0 * 64 + lane];
                uint2 v1 = base[(size_t)s1 * 64 + lane];
                uint2 v2 = base[(size_t)s2 * 64 + lane];
                uint2 v3 = base[(size_t)s3 * 64 + lane];
                a0[0] += bf2f(v0.x & 0xffffu); a0[1] += bf2f(v0.x >> 16);
                a0[2] += bf2f(v0.y & 0xffffu); a0[3] += bf2f(v0.y >> 16);
                a1[0] += bf2f(v1.x & 0xffffu); a1[1] += bf2f(v1.x >> 16);
                a1[2] += bf2f(v1.y & 0xffffu); a1[3] += bf2f(v1.y >> 16);
                a2[0] += bf2f(v2.x & 0xffffu); a2[1] += bf2f(v2.x >> 16);
                a2[2] += bf2f(v2.y & 0xffffu); a2[3] += bf2f(v2.y >> 16);
                a3[0] += bf2f(v3.x & 0xffffu); a3[1] += bf2f(v3.x >> 16);
                a3[2] += bf2f(v3.y & 0xffffu); a3[3] += bf2f(v3.y >> 16);
            }
        }
        float r0 = (a0[0] + a1[0]) + (a2[0] + a3[0]);
        float r1 = (a0[1] + a1[1]) + (a2[1] + a3[1]);
        float r2 = (a0[2] + a1[2]) + (a2[2] + a3[2]);
        float r3 = (a0[3] + a1[3]) + (a2[3] + a3[3]);
        uint2 o;
        o.x = pack2(r0 * sc, r1 * sc);
        o.y = pack2(r2 * sc, r3 * sc);
        reinterpret_cast<uint2*>(agg)[(size_t)w * 64 + lane] = o;
    } else {   // D == 128: row = 64 uints (4B/lane)
        const unsigned int* base = reinterpret_cast<const unsigned int*>(feat);
        float a0[2] = {}, a1[2] = {}, a2[2] = {}, a3[2] = {};
        for (int e0 = 0; e0 < deg; e0 += 64) {
            const int chunk = min(deg - e0, 64);
            int pv = (lane < chunk) ? perm[beg + e0 + lane] : 0;
            int i = chunk & 3;
            if (i > 0) {
                int s = __builtin_amdgcn_readlane(pv, 0);
                unsigned int v = base[(size_t)s * 64 + lane];
                a1[0] += bf2f(v & 0xffffu); a1[1] += bf2f(v >> 16);
            }
            if (i > 1) {
                int s = __builtin_amdgcn_readlane(pv, 1);
                unsigned int v = base[(size_t)s * 64 + lane];
                a2[0] += bf2f(v & 0xffffu); a2[1] += bf2f(v >> 16);
            }
            if (i > 2) {
                int s = __builtin_amdgcn_readlane(pv, 2);
                unsigned int v = base[(size_t)s * 64 + lane];
                a3[0] += bf2f(v & 0xffffu); a3[1] += bf2f(v >> 16);
            }
            for (; i + 4 <= chunk; i += 4) {
                int s0 = __builtin_amdgcn_readlane(pv, i + 0);
                int s1 = __builtin_amdgcn_readlane(pv, i + 1);
                int s2 = __builtin_amdgcn_readlane(pv, i + 2);
                int s3 = __builtin_amdgcn_readlane(pv, i + 3);
                unsigned int v0 = base[(size_t)s0 * 64 + lane];
                unsigned int v1 = base[(size_t)s1 * 64 + lane];
                unsigned int v2 = base[(size_t)s2 * 64 + lane];
                unsigned int v3 = base[(size_t)s3 * 64 + lane];
                a0[0] += bf2f(v0 & 0xffffu); a0[1] += bf2f(v0 >> 16);
                a1[0] += bf2f(v1 & 0xffffu); a1[1] += bf2f(v1 >> 16);
                a2[0] += bf2f(v2 & 0xffffu); a2[1] += bf2f(v2 >> 16);
                a3[0] += bf2f(v3 & 0xffffu); a3[1] += bf2f(v3 >> 16);
            }
        }
        float r0 = (a0[0] + a1[0]) + (a2[0] + a3[0]);
        float r1 = (a0[1] + a1[1]) + (a2[1] + a3[1]);
        reinterpret_cast<unsigned int*>(agg)[(size_t)w * 64 + lane] = pack2(r0 * sc, r1 * sc);
    }
}

// ---------------- bf16 MFMA fused SAGE GEMM (128x256, 8 waves, 3-buf) ------
// out[m,c] = relu( [agg | xr][m,:] @ WT^T + bias ),  WT is [256][2KP] bf16.
// Block: 128 rows x 256 cols (full N), 512 threads = 8 waves (2 wr x 4 wc),
// wave tile 64x64, BK=32, 16x16x32 MFMA. A read once from HBM.
// LDS: 3 buffers x (A[128][32] 8KB + B[256][32] 16KB) = 72 KB.
// Swizzle (verified R9, conflicts=0): LDS chunk c holds global chunk
// c ^ ((row>>1)&3); staging source chunk = (l&3) ^ ((l>>3)&3).
// Pipeline: 2-deep prefetch, vmcnt(6) steady (3 loads/lane/tile).
template <int KP, bool WF, bool WB>
__global__ __launch_bounds__(512) void sage_mfma_gemm(
    const unsigned short* __restrict__ Aagg,  // [M, KP] bf16
    const unsigned short* __restrict__ Axr,   // [M, KP] bf16
    const unsigned short* __restrict__ WT,    // [256, 2KP] bf16
    const float* __restrict__ bias,
    float* __restrict__ outf,                 // used if WF
    unsigned short* __restrict__ outb,        // used if WB
    int M)
{
    __shared__ __align__(16) unsigned short As[3 * 4096];   // 3 x [128][32]
    __shared__ __align__(16) unsigned short Bs[3 * 8192];   // 3 x [256][32]

    const int t   = threadIdx.x;
    const int l   = t & 63;
    const int wid = t >> 6;          // 0..7
    const int wr  = wid >> 2;        // 0..1
    const int wc  = wid & 3;         // 0..3
    const int m0  = blockIdx.x * 128;

    const int rin = l >> 2;                       // row within 16-row chunk
    const int csw = (l & 3) ^ ((l >> 3) & 3);     // swizzled source chunk

    // this wave stages chunks wid*3 .. wid*3+2 (24 total: 8 A + 16 B)
    const int sc0 = wid * 3, sc1 = sc0 + 1, sc2 = sc0 + 2;

    constexpr int K2 = 2 * KP;
    constexpr int KT = K2 / 32;

    auto stageChunk = [&](int buf, int kt, int ch) {
        const int kb = kt * 32;
        if (ch < 8) {               // A chunk: rows m0+ch*16 .. +16
            const unsigned short* Asrc;
            int kk;
            if (kb < KP) { Asrc = Aagg; kk = kb; }
            else         { Asrc = Axr;  kk = kb - KP; }
            int row = m0 + ch * 16 + rin; if (row >= M) row = M - 1;
            gload16(Asrc + (size_t)row * KP + kk + csw * 8,
                    As + buf * 4096 + ch * 512);
        } else {                    // B chunk: WT rows (ch-8)*16 .. +16
            int row = (ch - 8) * 16 + rin;
            gload16(WT + (size_t)row * K2 + kb + csw * 8,
                    Bs + buf * 8192 + (ch - 8) * 512);
        }
    };
    auto stage = [&](int buf, int kt) {
        stageChunk(buf, kt, sc0);
        stageChunk(buf, kt, sc1);
        stageChunk(buf, kt, sc2);
    };

    // fragment-read offsets: row fr = l&15, logical chunk g = l>>4,
    // lds chunk = g ^ ((fr>>1)&3) = (l>>4) ^ ((l>>1)&3)
    const int fr  = l & 15;
    const int swz = ((l >> 4) ^ ((l >> 1) & 3)) * 8;    // ushort units
    const int aOff = (wr * 64 + fr) * 32 + swz;
    const int bOff = (wc * 64 + fr) * 32 + swz;

    f32x4 acc[4][4] = {};

    stage(0, 0);
    stage(1, 1);

    int cur = 0;
    for (int kt = 0; kt < KT; ++kt) {
        if (kt + 2 < KT) {
            int nb = cur + 2; if (nb >= 3) nb -= 3;
            stage(nb, kt + 2);      // 2-deep prefetch
            asm volatile("s_waitcnt vmcnt(6)" ::: "memory");   // tile kt landed
        } else if (kt + 1 < KT) {
            asm volatile("s_waitcnt vmcnt(3)" ::: "memory");
        } else {
            asm volatile("s_waitcnt vmcnt(0)" ::: "memory");
        }
        __builtin_amdgcn_s_barrier();            // raw: no auto drain
        __builtin_amdgcn_sched_barrier(0);

        const unsigned short* Ard = As + cur * 4096 + aOff;
        const unsigned short* Brd = Bs + cur * 8192 + bOff;
        short8 af[4], bf[4];
        #pragma unroll
        for (int i = 0; i < 4; ++i)
            af[i] = *reinterpret_cast<const short8*>(Ard + i * 512);
        #pragma unroll
        for (int i = 0; i < 4; ++i)
            bf[i] = *reinterpret_cast<const short8*>(Brd + i * 512);
        #pragma unroll
        for (int i = 0; i < 4; ++i)
            #pragma unroll
            for (int j = 0; j < 4; ++j)
                acc[i][j] = __builtin_amdgcn_mfma_f32_16x16x32_bf16(
                    af[i], bf[j], acc[i][j], 0, 0, 0);

        asm volatile("s_waitcnt lgkmcnt(0)" ::: "memory");  // reads done
        __builtin_amdgcn_s_barrier();            // safe to overwrite cur-1
        __builtin_amdgcn_sched_barrier(0);
        cur = (cur == 2) ? 0 : cur + 1;
    }

    // epilogue: C/D layout col = l&15, row = (l>>4)*4 + reg
    const int rq = (l >> 4) * 4;
    #pragma unroll
    for (int fn = 0; fn < 4; ++fn) {
        const int col = wc * 64 + fn * 16 + fr;
        const float bb = bias[col];
        #pragma unroll
        for (int fm = 0; fm < 4; ++fm) {
            const int rbase = m0 + wr * 64 + fm * 16 + rq;
            #pragma unroll
            for (int j = 0; j < 4; ++j) {
                const int r = rbase + j;
                if (r < M) {
                    float v = fmaxf(acc[fm][fn][j] + bb, 0.f);
                    if (WF) outf[(size_t)r * DHID + col] = v;
                    if (WB) outb[(size_t)r * DHID + col] = f2b(v);
                }
            }
        }
    }
}

extern "C" void kernel_launch(void* const* d_in, const int* in_sizes, int n_in,
                              void* d_out, int out_size, void* d_ws, size_t ws_size,
                              hipStream_t stream)
{
    const float* x   = (const float*)d_in[0];
    const int*   ei  = (const int*)d_in[1];
    const int*   src = ei;
    const int*   dst = ei + NE;
    const float* Wl0 = (const float*)d_in[2];
    const float* Wr0 = (const float*)d_in[3];
    const float* b0  = (const float*)d_in[4];
    const float* Wl1 = (const float*)d_in[5];
    const float* Wr1 = (const float*)d_in[6];
    const float* b1  = (const float*)d_in[7];
    float* out = (float*)d_out;

    // workspace layout (bytes):
    //   hist    : @0          400384
    //   offs    : @400384     400640
    //   perm    : @801024     2500352
    //   bsum    : @3301376    4096
    //   bpre    : @3305472    4096
    //   cursor  : @3309568    400384
    //   WT0     : @3709952    131072
    //   WT1     : @3841024    262144
    //   xb      : @4103168    25600000
    //   h0b     : @29703168   51200000
    //   aggb    : @80903168   51200000
    // total ~132.1 MB
    char* ws = (char*)d_ws;
    int*            hist   = (int*)(ws);
    int*            offs   = (int*)(ws + 400384);
    int*            perm   = (int*)(ws + 801024);
    int*            bsum   = (int*)(ws + 3301376);
    int*            bpre   = (int*)(ws + 3305472);
    int*            cursor = (int*)(ws + 3309568);
    unsigned short* WT0    = (unsigned short*)(ws + 3709952);
    unsigned short* WT1    = (unsigned short*)(ws + 3841024);
    unsigned short* xb     = (unsigned short*)(ws + 4103168);
    unsigned short* h0b    = (unsigned short*)(ws + 29703168);
    unsigned short* aggb   = (unsigned short*)(ws + 80903168);

    zero_kernel<<<(NN + 255) / 256, 256, 0, stream>>>(hist, NN);
    hist_kernel<<<(NE + 255) / 256, 256, 0, stream>>>(dst, hist);
    chunk_sum_kernel<<<NB, 256, 0, stream>>>(hist, bsum);
    scan_bsum_kernel<<<1, 512, 0, stream>>>(bsum, bpre);
    scatter_offs_kernel<<<NB, 256, 0, stream>>>(hist, bpre, offs, cursor);
    perm_kernel<<<(NE + 255) / 256, 256, 0, stream>>>(src, dst, cursor, perm);

    prep_all_kernel<<<CONV_BLKS + 256 + 512, 256, 0, stream>>>(
        x, xb, Wl0, Wr0, WT0, Wl1, Wr1, WT1);

    constexpr int NWBLK = (NN * 64) / 256;   // 25000 exactly
    const int GEMM_BLKS = (NN + 127) / 128;  // 782, full N per block

    // ---- layer 0 ----
    gather_mean_kernel<DIN><<<NWBLK, 256, 0, stream>>>(offs, perm, xb, aggb);
    sage_mfma_gemm<DIN, false, true><<<GEMM_BLKS, 512, 0, stream>>>(
        aggb, xb, WT0, b0, nullptr, h0b, NN);

    // ---- layer 1 ----
    gather_mean_kernel<DHID><<<NWBLK, 256, 0, stream>>>(offs, perm, h0b, aggb);
    sage_mfma_gemm<DHID, true, false><<<GEMM_BLKS, 512, 0, stream>>>(
        aggb, h0b, WT1, b1, out, nullptr, NN);
}

// Round 11
// 269.707 us; speedup vs baseline: 1.1253x; 1.0149x over previous
//
#include <hip/hip_runtime.h>

// GraphSAGE 2-layer: CSR gather-mean (bf16) + bf16 MFMA fused GEMMs.
// R11: (a) GEMM 2-buffer 48KB LDS -> 3 blocks/CU (was 3-buf 72KB, 2/CU);
//      (b) gather: 32-lane rows (16B/lane), even/odd edge halves with
//          masked-fma + shfl_xor(32) merge — half the trips, 2x MLP/lane;
//      (c) zero_kernel merged into prep_all (10 launches).

constexpr int NN   = 100000;
constexpr int NE   = 625000;
constexpr int DIN  = 128;
constexpr int DHID = 256;
constexpr int NB   = (NN + 255) / 256;          // 391 scan chunks
constexpr int CONV_BLKS = NN * DIN / 8 / 256;   // 6250 (exact)

using short8 = __attribute__((ext_vector_type(8))) short;
using f32x4  = __attribute__((ext_vector_type(4))) float;

__device__ __forceinline__ float bf2f(unsigned int u) {
    return __uint_as_float(u << 16);
}
__device__ __forceinline__ unsigned short f2b(float f) {
    unsigned int u = __float_as_uint(f);
    unsigned int r = (u + 0x7fffu + ((u >> 16) & 1u)) >> 16;   // RNE
    return (unsigned short)r;
}
__device__ __forceinline__ unsigned int pack2(float lo, float hi) {
    return (unsigned int)f2b(lo) | ((unsigned int)f2b(hi) << 16);
}
__device__ __forceinline__ void gload16(const void* g, void* lds) {
    __builtin_amdgcn_global_load_lds(
        (const __attribute__((address_space(1))) void*)g,
        (__attribute__((address_space(3))) void*)lds, 16, 0, 0);
}

// ---------------- CSR build ------------------------------------------------
__global__ __launch_bounds__(256) void hist_kernel(const int* __restrict__ dst,
                                                   int* __restrict__ hist)
{
    int t = blockIdx.x * 256 + threadIdx.x;
    if (t < NE) atomicAdd(&hist[dst[t]], 1);
}

__global__ __launch_bounds__(256) void chunk_sum_kernel(const int* __restrict__ hist,
                                                        int* __restrict__ bsum)
{
    __shared__ int s[256];
    int i = blockIdx.x * 256 + threadIdx.x;
    s[threadIdx.x] = (i < NN) ? hist[i] : 0;
    __syncthreads();
    for (int off = 128; off > 0; off >>= 1) {
        if (threadIdx.x < off) s[threadIdx.x] += s[threadIdx.x + off];
        __syncthreads();
    }
    if (threadIdx.x == 0) bsum[blockIdx.x] = s[0];
}

__global__ __launch_bounds__(512) void scan_bsum_kernel(const int* __restrict__ bsum,
                                                        int* __restrict__ bpre)
{
    __shared__ int s[512];
    int t = threadIdx.x;
    int v = (t < NB) ? bsum[t] : 0;
    s[t] = v;
    __syncthreads();
    for (int off = 1; off < 512; off <<= 1) {
        int u = (t >= off) ? s[t - off] : 0;
        __syncthreads();
        s[t] += u;
        __syncthreads();
    }
    if (t < NB) bpre[t] = s[t] - v;        // exclusive prefix
}

__global__ __launch_bounds__(256) void scatter_offs_kernel(const int* __restrict__ hist,
                                                           const int* __restrict__ bpre,
                                                           int* __restrict__ offs,
                                                           int* __restrict__ cursor)
{
    __shared__ int s[256];
    int t = threadIdx.x;
    int i = blockIdx.x * 256 + t;
    int v = (i < NN) ? hist[i] : 0;
    s[t] = v;
    __syncthreads();
    for (int off = 1; off < 256; off <<= 1) {
        int u = (t >= off) ? s[t - off] : 0;
        __syncthreads();
        s[t] += u;
        __syncthreads();
    }
    int excl = s[t] - v + bpre[blockIdx.x];
    if (i < NN) {
        offs[i]   = excl;
        cursor[i] = excl;
    }
    if (i == NN - 1) offs[NN] = NE;
}

__global__ __launch_bounds__(256) void perm_kernel(const int* __restrict__ src,
                                                   const int* __restrict__ dst,
                                                   int* __restrict__ cursor,
                                                   int* __restrict__ perm)
{
    int t = blockIdx.x * 256 + threadIdx.x;
    if (t < NE) {
        int p = atomicAdd(&cursor[dst[t]], 1);
        perm[p] = src[t];
    }
}

// ---------------- merged prep: x->bf16, WT0, WT1, zero hist ----------------
__global__ __launch_bounds__(256) void prep_all_kernel(
    const float* __restrict__ x, unsigned short* __restrict__ xb,
    const float* __restrict__ Wl0, const float* __restrict__ Wr0,
    unsigned short* __restrict__ WT0,
    const float* __restrict__ Wl1, const float* __restrict__ Wr1,
    unsigned short* __restrict__ WT1,
    int* __restrict__ hist)
{
    int b = blockIdx.x;
    if (b < CONV_BLKS) {
        int t = b * 256 + threadIdx.x;          // [0, 1.6M) exact
        float4 v0 = reinterpret_cast<const float4*>(x)[t * 2 + 0];
        float4 v1 = reinterpret_cast<const float4*>(x)[t * 2 + 1];
        uint4 o;
        o.x = pack2(v0.x, v0.y); o.y = pack2(v0.z, v0.w);
        o.z = pack2(v1.x, v1.y); o.w = pack2(v1.z, v1.w);
        reinterpret_cast<uint4*>(xb)[t] = o;
    } else if (b < CONV_BLKS + 256) {
        int t = (b - CONV_BLKS) * 256 + threadIdx.x;   // [0, 65536)
        int n = t >> 8, k = t & 255;
        float v = (k < DIN) ? Wl0[(size_t)k * DHID + n]
                            : Wr0[(size_t)(k - DIN) * DHID + n];
        WT0[t] = f2b(v);
    } else if (b < CONV_BLKS + 256 + 512) {
        int t = (b - CONV_BLKS - 256) * 256 + threadIdx.x;   // [0, 131072)
        int n = t >> 9, k = t & 511;
        float v = (k < DHID) ? Wl1[(size_t)k * DHID + n]
                             : Wr1[(size_t)(k - DHID) * DHID + n];
        WT1[t] = f2b(v);
    } else {
        int t = (b - CONV_BLKS - 256 - 512) * 256 + threadIdx.x;
        if (t < NN) hist[t] = 0;
    }
}

// ---------------- gather-mean aggregation (32-lane rows, edge pairs) -------
// One wave per node. Lane l: half h = l>>5 (0: even edges, 1: odd edges),
// col-chunk c = l&31. Masked-fma tail; final __shfl_xor(32) merges halves;
// lanes 0..31 write the vectorized row.
template <int D>
__global__ __launch_bounds__(256) void gather_mean_kernel(
    const int* __restrict__ offs, const int* __restrict__ perm,
    const unsigned short* __restrict__ feat, unsigned short* __restrict__ agg)
{
    const int w = (blockIdx.x * 256 + threadIdx.x) >> 6;
    const int l = threadIdx.x & 63;
    const int h = l >> 5;
    const int c = l & 31;
    if (w >= NN) return;
    const int beg = offs[w], end = offs[w + 1];
    const int deg = end - beg;
    const float sc = 1.0f / (float)(deg > 1 ? deg : 1);

    if constexpr (D == 256) {
        const uint4* base = reinterpret_cast<const uint4*>(feat);  // 32/row
        float A0[8] = {}, A1[8] = {};
        for (int e0 = 0; e0 < deg; e0 += 64) {
            const int chunk = min(deg - e0, 64);
            int pv = (l < chunk) ? perm[beg + e0 + l] : 0;
            auto dopair = [&](float* A, int p) {
                int sA = __builtin_amdgcn_readlane(pv, 2 * p);
                int sB = __builtin_amdgcn_readlane(pv, 2 * p + 1);
                int e  = 2 * p + h;
                int s  = h ? sB : sA;
                float m = (e < chunk) ? 1.0f : 0.0f;
                uint4 v = base[(size_t)s * 32 + c];
                A[0] = fmaf(bf2f(v.x & 0xffffu), m, A[0]);
                A[1] = fmaf(bf2f(v.x >> 16),     m, A[1]);
                A[2] = fmaf(bf2f(v.y & 0xffffu), m, A[2]);
                A[3] = fmaf(bf2f(v.y >> 16),     m, A[3]);
                A[4] = fmaf(bf2f(v.z & 0xffffu), m, A[4]);
                A[5] = fmaf(bf2f(v.z >> 16),     m, A[5]);
                A[6] = fmaf(bf2f(v.w & 0xffffu), m, A[6]);
                A[7] = fmaf(bf2f(v.w >> 16),     m, A[7]);
            };
            const int np = (chunk + 1) >> 1;
            int p = 0;
            if (np & 1) { dopair(A1, 0); p = 1; }
            for (; p < np; p += 2) { dopair(A0, p); dopair(A1, p + 1); }
        }
        float r[8];
        #pragma unroll
        for (int j = 0; j < 8; ++j) {
            r[j] = A0[j] + A1[j];
            r[j] += __shfl_xor(r[j], 32);
            r[j] *= sc;
        }
        if (l < 32) {
            uint4 o;
            o.x = pack2(r[0], r[1]); o.y = pack2(r[2], r[3]);
            o.z = pack2(r[4], r[5]); o.w = pack2(r[6], r[7]);
            reinterpret_cast<uint4*>(agg)[(size_t)w * 32 + c] = o;
        }
    } else {   // D == 128: 32 x uint2 per row
        const uint2* base = reinterpret_cast<const uint2*>(feat);
        float A0[4] = {}, A1[4] = {};
        for (int e0 = 0; e0 < deg; e0 += 64) {
            const int chunk = min(deg - e0, 64);
            int pv = (l < chunk) ? perm[beg + e0 + l] : 0;
            auto dopair = [&](float* A, int p) {
                int sA = __builtin_amdgcn_readlane(pv, 2 * p);
                int sB = __builtin_amdgcn_readlane(pv, 2 * p + 1);
                int e  = 2 * p + h;
                int s  = h ? sB : sA;
                float m = (e < chunk) ? 1.0f : 0.0f;
                uint2 v = base[(size_t)s * 32 + c];
                A[0] = fmaf(bf2f(v.x & 0xffffu), m, A[0]);
                A[1] = fmaf(bf2f(v.x >> 16),     m, A[1]);
                A[2] = fmaf(bf2f(v.y & 0xffffu), m, A[2]);
                A[3] = fmaf(bf2f(v.y >> 16),     m, A[3]);
            };
            const int np = (chunk + 1) >> 1;
            int p = 0;
            if (np & 1) { dopair(A1, 0); p = 1; }
            for (; p < np; p += 2) { dopair(A0, p); dopair(A1, p + 1); }
        }
        float r[4];
        #pragma unroll
        for (int j = 0; j < 4; ++j) {
            r[j] = A0[j] + A1[j];
            r[j] += __shfl_xor(r[j], 32);
            r[j] *= sc;
        }
        if (l < 32) {
            uint2 o;
            o.x = pack2(r[0], r[1]); o.y = pack2(r[2], r[3]);
            reinterpret_cast<uint2*>(agg)[(size_t)w * 32 + c] = o;
        }
    }
}

// ---------------- bf16 MFMA fused SAGE GEMM (128x256, 8 waves, 2-buf) ------
// out[m,c] = relu( [agg | xr][m,:] @ WT^T + bias ),  WT is [256][2KP] bf16.
// 512 threads = 8 waves (2 wr x 4 wc), wave tile 64x64, BK=32.
// LDS: 2 buffers x (A 8KB + B 16KB) = 48 KB -> 3 blocks/CU.
// Swizzle (verified, conflicts=0): LDS chunk c holds global chunk
// c ^ ((row>>1)&3); staging source chunk = (l&3) ^ ((l>>3)&3).
// Pipeline: 1-deep prefetch, vmcnt(3) steady, raw barriers.
template <int KP, bool WF, bool WB>
__global__ __launch_bounds__(512) void sage_mfma_gemm(
    const unsigned short* __restrict__ Aagg,  // [M, KP] bf16
    const unsigned short* __restrict__ Axr,   // [M, KP] bf16
    const unsigned short* __restrict__ WT,    // [256, 2KP] bf16
    const float* __restrict__ bias,
    float* __restrict__ outf,                 // used if WF
    unsigned short* __restrict__ outb,        // used if WB
    int M)
{
    __shared__ __align__(16) unsigned short As[2 * 4096];   // 2 x [128][32]
    __shared__ __align__(16) unsigned short Bs[2 * 8192];   // 2 x [256][32]

    const int t   = threadIdx.x;
    const int l   = t & 63;
    const int wid = t >> 6;          // 0..7
    const int wr  = wid >> 2;        // 0..1
    const int wc  = wid & 3;         // 0..3
    const int m0  = blockIdx.x * 128;

    const int rin = l >> 2;                       // row within 16-row chunk
    const int csw = (l & 3) ^ ((l >> 3) & 3);     // swizzled source chunk

    // this wave stages chunks wid*3 .. wid*3+2 (24 total: 8 A + 16 B)
    const int sc0 = wid * 3, sc1 = sc0 + 1, sc2 = sc0 + 2;

    constexpr int K2 = 2 * KP;
    constexpr int KT = K2 / 32;

    auto stageChunk = [&](int buf, int kt, int ch) {
        const int kb = kt * 32;
        if (ch < 8) {               // A chunk: rows m0+ch*16 .. +16
            const unsigned short* Asrc;
            int kk;
            if (kb < KP) { Asrc = Aagg; kk = kb; }
            else         { Asrc = Axr;  kk = kb - KP; }
            int row = m0 + ch * 16 + rin; if (row >= M) row = M - 1;
            gload16(Asrc + (size_t)row * KP + kk + csw * 8,
                    As + buf * 4096 + ch * 512);
        } else {                    // B chunk: WT rows (ch-8)*16 .. +16
            int row = (ch - 8) * 16 + rin;
            gload16(WT + (size_t)row * K2 + kb + csw * 8,
                    Bs + buf * 8192 + (ch - 8) * 512);
        }
    };
    auto stage = [&](int buf, int kt) {
        stageChunk(buf, kt, sc0);
        stageChunk(buf, kt, sc1);
        stageChunk(buf, kt, sc2);
    };

    // fragment-read offsets: row fr = l&15, logical chunk g = l>>4,
    // lds chunk = g ^ ((fr>>1)&3) = (l>>4) ^ ((l>>1)&3)
    const int fr  = l & 15;
    const int swz = ((l >> 4) ^ ((l >> 1) & 3)) * 8;    // ushort units
    const int aOff = (wr * 64 + fr) * 32 + swz;
    const int bOff = (wc * 64 + fr) * 32 + swz;

    f32x4 acc[4][4] = {};

    stage(0, 0);

    int cur = 0;
    for (int kt = 0; kt < KT; ++kt) {
        if (kt + 1 < KT) {
            stage(cur ^ 1, kt + 1);   // 1-deep prefetch
            asm volatile("s_waitcnt vmcnt(3)" ::: "memory");   // tile kt landed
        } else {
            asm volatile("s_waitcnt vmcnt(0)" ::: "memory");
        }
        __builtin_amdgcn_s_barrier();            // raw: no auto drain
        __builtin_amdgcn_sched_barrier(0);

        const unsigned short* Ard = As + cur * 4096 + aOff;
        const unsigned short* Brd = Bs + cur * 8192 + bOff;
        short8 af[4], bf[4];
        #pragma unroll
        for (int i = 0; i < 4; ++i)
            af[i] = *reinterpret_cast<const short8*>(Ard + i * 512);
        #pragma unroll
        for (int i = 0; i < 4; ++i)
            bf[i] = *reinterpret_cast<const short8*>(Brd + i * 512);
        #pragma unroll
        for (int i = 0; i < 4; ++i)
            #pragma unroll
            for (int j = 0; j < 4; ++j)
                acc[i][j] = __builtin_amdgcn_mfma_f32_16x16x32_bf16(
                    af[i], bf[j], acc[i][j], 0, 0, 0);

        asm volatile("s_waitcnt lgkmcnt(0)" ::: "memory");  // reads done
        __builtin_amdgcn_s_barrier();            // safe to overwrite cur
        __builtin_amdgcn_sched_barrier(0);
        cur ^= 1;
    }

    // epilogue: C/D layout col = l&15, row = (l>>4)*4 + reg
    const int rq = (l >> 4) * 4;
    #pragma unroll
    for (int fn = 0; fn < 4; ++fn) {
        const int col = wc * 64 + fn * 16 + fr;
        const float bb = bias[col];
        #pragma unroll
        for (int fm = 0; fm < 4; ++fm) {
            const int rbase = m0 + wr * 64 + fm * 16 + rq;
            #pragma unroll
            for (int j = 0; j < 4; ++j) {
                const int r = rbase + j;
                if (r < M) {
                    float v = fmaxf(acc[fm][fn][j] + bb, 0.f);
                    if (WF) outf[(size_t)r * DHID + col] = v;
                    if (WB) outb[(size_t)r * DHID + col] = f2b(v);
                }
            }
        }
    }
}

extern "C" void kernel_launch(void* const* d_in, const int* in_sizes, int n_in,
                              void* d_out, int out_size, void* d_ws, size_t ws_size,
                              hipStream_t stream)
{
    const float* x   = (const float*)d_in[0];
    const int*   ei  = (const int*)d_in[1];
    const int*   src = ei;
    const int*   dst = ei + NE;
    const float* Wl0 = (const float*)d_in[2];
    const float* Wr0 = (const float*)d_in[3];
    const float* b0  = (const float*)d_in[4];
    const float* Wl1 = (const float*)d_in[5];
    const float* Wr1 = (const float*)d_in[6];
    const float* b1  = (const float*)d_in[7];
    float* out = (float*)d_out;

    // workspace layout (bytes):
    //   hist    : @0          400384
    //   offs    : @400384     400640
    //   perm    : @801024     2500352
    //   bsum    : @3301376    4096
    //   bpre    : @3305472    4096
    //   cursor  : @3309568    400384
    //   WT0     : @3709952    131072
    //   WT1     : @3841024    262144
    //   xb      : @4103168    25600000
    //   h0b     : @29703168   51200000
    //   aggb    : @80903168   51200000
    // total ~132.1 MB
    char* ws = (char*)d_ws;
    int*            hist   = (int*)(ws);
    int*            offs   = (int*)(ws + 400384);
    int*            perm   = (int*)(ws + 801024);
    int*            bsum   = (int*)(ws + 3301376);
    int*            bpre   = (int*)(ws + 3305472);
    int*            cursor = (int*)(ws + 3309568);
    unsigned short* WT0    = (unsigned short*)(ws + 3709952);
    unsigned short* WT1    = (unsigned short*)(ws + 3841024);
    unsigned short* xb     = (unsigned short*)(ws + 4103168);
    unsigned short* h0b    = (unsigned short*)(ws + 29703168);
    unsigned short* aggb   = (unsigned short*)(ws + 80903168);

    // prep (also zeroes hist), then CSR chain
    prep_all_kernel<<<CONV_BLKS + 256 + 512 + NB, 256, 0, stream>>>(
        x, xb, Wl0, Wr0, WT0, Wl1, Wr1, WT1, hist);
    hist_kernel<<<(NE + 255) / 256, 256, 0, stream>>>(dst, hist);
    chunk_sum_kernel<<<NB, 256, 0, stream>>>(hist, bsum);
    scan_bsum_kernel<<<1, 512, 0, stream>>>(bsum, bpre);
    scatter_offs_kernel<<<NB, 256, 0, stream>>>(hist, bpre, offs, cursor);
    perm_kernel<<<(NE + 255) / 256, 256, 0, stream>>>(src, dst, cursor, perm);

    constexpr int NWBLK = (NN * 64) / 256;   // 25000 exactly
    const int GEMM_BLKS = (NN + 127) / 128;  // 782, full N per block

    // ---- layer 0 ----
    gather_mean_kernel<DIN><<<NWBLK, 256, 0, stream>>>(offs, perm, xb, aggb);
    sage_mfma_gemm<DIN, false, true><<<GEMM_BLKS, 512, 0, stream>>>(
        aggb, xb, WT0, b0, nullptr, h0b, NN);

    // ---- layer 1 ----
    gather_mean_kernel<DHID><<<NWBLK, 256, 0, stream>>>(offs, perm, h0b, aggb);
    sage_mfma_gemm<DHID, true, false><<<GEMM_BLKS, 512, 0, stream>>>(
        aggb, h0b, WT1, b1, out, nullptr, NN);
}

// Round 12
// 266.810 us; speedup vs baseline: 1.1375x; 1.0109x over previous
//
#include <hip/hip_runtime.h>

// GraphSAGE 2-layer: CSR gather-mean (bf16) + bf16 MFMA fused GEMMs.
// R12: GEMM 256x256 tile, 1024 thr = 16 waves (4x4 of 64x64), 2-buf BK=32,
//      LDS 64KB -> 2 blocks/CU = 32 waves/CU (max). Inner loop identical
//      to R11 (verified). Staging: 2 chunks/wave, steady vmcnt(2).

constexpr int NN   = 100000;
constexpr int NE   = 625000;
constexpr int DIN  = 128;
constexpr int DHID = 256;
constexpr int NB   = (NN + 255) / 256;          // 391 scan chunks
constexpr int CONV_BLKS = NN * DIN / 8 / 256;   // 6250 (exact)

using short8 = __attribute__((ext_vector_type(8))) short;
using f32x4  = __attribute__((ext_vector_type(4))) float;

__device__ __forceinline__ float bf2f(unsigned int u) {
    return __uint_as_float(u << 16);
}
__device__ __forceinline__ unsigned short f2b(float f) {
    unsigned int u = __float_as_uint(f);
    unsigned int r = (u + 0x7fffu + ((u >> 16) & 1u)) >> 16;   // RNE
    return (unsigned short)r;
}
__device__ __forceinline__ unsigned int pack2(float lo, float hi) {
    return (unsigned int)f2b(lo) | ((unsigned int)f2b(hi) << 16);
}
__device__ __forceinline__ void gload16(const void* g, void* lds) {
    __builtin_amdgcn_global_load_lds(
        (const __attribute__((address_space(1))) void*)g,
        (__attribute__((address_space(3))) void*)lds, 16, 0, 0);
}

// ---------------- CSR build ------------------------------------------------
__global__ __launch_bounds__(256) void hist_kernel(const int* __restrict__ dst,
                                                   int* __restrict__ hist)
{
    int t = blockIdx.x * 256 + threadIdx.x;
    if (t < NE) atomicAdd(&hist[dst[t]], 1);
}

__global__ __launch_bounds__(256) void chunk_sum_kernel(const int* __restrict__ hist,
                                                        int* __restrict__ bsum)
{
    __shared__ int s[256];
    int i = blockIdx.x * 256 + threadIdx.x;
    s[threadIdx.x] = (i < NN) ? hist[i] : 0;
    __syncthreads();
    for (int off = 128; off > 0; off >>= 1) {
        if (threadIdx.x < off) s[threadIdx.x] += s[threadIdx.x + off];
        __syncthreads();
    }
    if (threadIdx.x == 0) bsum[blockIdx.x] = s[0];
}

__global__ __launch_bounds__(512) void scan_bsum_kernel(const int* __restrict__ bsum,
                                                        int* __restrict__ bpre)
{
    __shared__ int s[512];
    int t = threadIdx.x;
    int v = (t < NB) ? bsum[t] : 0;
    s[t] = v;
    __syncthreads();
    for (int off = 1; off < 512; off <<= 1) {
        int u = (t >= off) ? s[t - off] : 0;
        __syncthreads();
        s[t] += u;
        __syncthreads();
    }
    if (t < NB) bpre[t] = s[t] - v;        // exclusive prefix
}

__global__ __launch_bounds__(256) void scatter_offs_kernel(const int* __restrict__ hist,
                                                           const int* __restrict__ bpre,
                                                           int* __restrict__ offs,
                                                           int* __restrict__ cursor)
{
    __shared__ int s[256];
    int t = threadIdx.x;
    int i = blockIdx.x * 256 + t;
    int v = (i < NN) ? hist[i] : 0;
    s[t] = v;
    __syncthreads();
    for (int off = 1; off < 256; off <<= 1) {
        int u = (t >= off) ? s[t - off] : 0;
        __syncthreads();
        s[t] += u;
        __syncthreads();
    }
    int excl = s[t] - v + bpre[blockIdx.x];
    if (i < NN) {
        offs[i]   = excl;
        cursor[i] = excl;
    }
    if (i == NN - 1) offs[NN] = NE;
}

__global__ __launch_bounds__(256) void perm_kernel(const int* __restrict__ src,
                                                   const int* __restrict__ dst,
                                                   int* __restrict__ cursor,
                                                   int* __restrict__ perm)
{
    int t = blockIdx.x * 256 + threadIdx.x;
    if (t < NE) {
        int p = atomicAdd(&cursor[dst[t]], 1);
        perm[p] = src[t];
    }
}

// ---------------- merged prep: x->bf16, WT0, WT1, zero hist ----------------
__global__ __launch_bounds__(256) void prep_all_kernel(
    const float* __restrict__ x, unsigned short* __restrict__ xb,
    const float* __restrict__ Wl0, const float* __restrict__ Wr0,
    unsigned short* __restrict__ WT0,
    const float* __restrict__ Wl1, const float* __restrict__ Wr1,
    unsigned short* __restrict__ WT1,
    int* __restrict__ hist)
{
    int b = blockIdx.x;
    if (b < CONV_BLKS) {
        int t = b * 256 + threadIdx.x;          // [0, 1.6M) exact
        float4 v0 = reinterpret_cast<const float4*>(x)[t * 2 + 0];
        float4 v1 = reinterpret_cast<const float4*>(x)[t * 2 + 1];
        uint4 o;
        o.x = pack2(v0.x, v0.y); o.y = pack2(v0.z, v0.w);
        o.z = pack2(v1.x, v1.y); o.w = pack2(v1.z, v1.w);
        reinterpret_cast<uint4*>(xb)[t] = o;
    } else if (b < CONV_BLKS + 256) {
        int t = (b - CONV_BLKS) * 256 + threadIdx.x;   // [0, 65536)
        int n = t >> 8, k = t & 255;
        float v = (k < DIN) ? Wl0[(size_t)k * DHID + n]
                            : Wr0[(size_t)(k - DIN) * DHID + n];
        WT0[t] = f2b(v);
    } else if (b < CONV_BLKS + 256 + 512) {
        int t = (b - CONV_BLKS - 256) * 256 + threadIdx.x;   // [0, 131072)
        int n = t >> 9, k = t & 511;
        float v = (k < DHID) ? Wl1[(size_t)k * DHID + n]
                             : Wr1[(size_t)(k - DHID) * DHID + n];
        WT1[t] = f2b(v);
    } else {
        int t = (b - CONV_BLKS - 256 - 512) * 256 + threadIdx.x;
        if (t < NN) hist[t] = 0;
    }
}

// ---------------- gather-mean aggregation (32-lane rows, edge pairs) -------
template <int D>
__global__ __launch_bounds__(256) void gather_mean_kernel(
    const int* __restrict__ offs, const int* __restrict__ perm,
    const unsigned short* __restrict__ feat, unsigned short* __restrict__ agg)
{
    const int w = (blockIdx.x * 256 + threadIdx.x) >> 6;
    const int l = threadIdx.x & 63;
    const int h = l >> 5;
    const int c = l & 31;
    if (w >= NN) return;
    const int beg = offs[w], end = offs[w + 1];
    const int deg = end - beg;
    const float sc = 1.0f / (float)(deg > 1 ? deg : 1);

    if constexpr (D == 256) {
        const uint4* base = reinterpret_cast<const uint4*>(feat);  // 32/row
        float A0[8] = {}, A1[8] = {};
        for (int e0 = 0; e0 < deg; e0 += 64) {
            const int chunk = min(deg - e0, 64);
            int pv = (l < chunk) ? perm[beg + e0 + l] : 0;
            auto dopair = [&](float* A, int p) {
                int sA = __builtin_amdgcn_readlane(pv, 2 * p);
                int sB = __builtin_amdgcn_readlane(pv, 2 * p + 1);
                int e  = 2 * p + h;
                int s  = h ? sB : sA;
                float m = (e < chunk) ? 1.0f : 0.0f;
                uint4 v = base[(size_t)s * 32 + c];
                A[0] = fmaf(bf2f(v.x & 0xffffu), m, A[0]);
                A[1] = fmaf(bf2f(v.x >> 16),     m, A[1]);
                A[2] = fmaf(bf2f(v.y & 0xffffu), m, A[2]);
                A[3] = fmaf(bf2f(v.y >> 16),     m, A[3]);
                A[4] = fmaf(bf2f(v.z & 0xffffu), m, A[4]);
                A[5] = fmaf(bf2f(v.z >> 16),     m, A[5]);
                A[6] = fmaf(bf2f(v.w & 0xffffu), m, A[6]);
                A[7] = fmaf(bf2f(v.w >> 16),     m, A[7]);
            };
            const int np = (chunk + 1) >> 1;
            int p = 0;
            if (np & 1) { dopair(A1, 0); p = 1; }
            for (; p < np; p += 2) { dopair(A0, p); dopair(A1, p + 1); }
        }
        float r[8];
        #pragma unroll
        for (int j = 0; j < 8; ++j) {
            r[j] = A0[j] + A1[j];
            r[j] += __shfl_xor(r[j], 32);
            r[j] *= sc;
        }
        if (l < 32) {
            uint4 o;
            o.x = pack2(r[0], r[1]); o.y = pack2(r[2], r[3]);
            o.z = pack2(r[4], r[5]); o.w = pack2(r[6], r[7]);
            reinterpret_cast<uint4*>(agg)[(size_t)w * 32 + c] = o;
        }
    } else {   // D == 128: 32 x uint2 per row
        const uint2* base = reinterpret_cast<const uint2*>(feat);
        float A0[4] = {}, A1[4] = {};
        for (int e0 = 0; e0 < deg; e0 += 64) {
            const int chunk = min(deg - e0, 64);
            int pv = (l < chunk) ? perm[beg + e0 + l] : 0;
            auto dopair = [&](float* A, int p) {
                int sA = __builtin_amdgcn_readlane(pv, 2 * p);
                int sB = __builtin_amdgcn_readlane(pv, 2 * p + 1);
                int e  = 2 * p + h;
                int s  = h ? sB : sA;
                float m = (e < chunk) ? 1.0f : 0.0f;
                uint2 v = base[(size_t)s * 32 + c];
                A[0] = fmaf(bf2f(v.x & 0xffffu), m, A[0]);
                A[1] = fmaf(bf2f(v.x >> 16),     m, A[1]);
                A[2] = fmaf(bf2f(v.y & 0xffffu), m, A[2]);
                A[3] = fmaf(bf2f(v.y >> 16),     m, A[3]);
            };
            const int np = (chunk + 1) >> 1;
            int p = 0;
            if (np & 1) { dopair(A1, 0); p = 1; }
            for (; p < np; p += 2) { dopair(A0, p); dopair(A1, p + 1); }
        }
        float r[4];
        #pragma unroll
        for (int j = 0; j < 4; ++j) {
            r[j] = A0[j] + A1[j];
            r[j] += __shfl_xor(r[j], 32);
            r[j] *= sc;
        }
        if (l < 32) {
            uint2 o;
            o.x = pack2(r[0], r[1]); o.y = pack2(r[2], r[3]);
            reinterpret_cast<uint2*>(agg)[(size_t)w * 32 + c] = o;
        }
    }
}

// ---------------- bf16 MFMA fused SAGE GEMM (256x256, 16 waves, 2-buf) -----
// out[m,c] = relu( [agg | xr][m,:] @ WT^T + bias ),  WT is [256][2KP] bf16.
// 1024 threads = 16 waves (4 wr x 4 wc), wave tile 64x64, BK=32.
// LDS: 2 buffers x (A 16KB + B 16KB) = 64 KB -> 2 blocks/CU = 32 waves/CU.
// Swizzle (verified, conflicts=0): LDS chunk c holds global chunk
// c ^ ((row>>1)&3); staging source chunk = (l&3) ^ ((l>>3)&3).
// Pipeline: 1-deep prefetch, steady vmcnt(2) (2 loads/lane/tile), raw bar.
template <int KP, bool WF, bool WB>
__global__ __launch_bounds__(1024) void sage_mfma_gemm(
    const unsigned short* __restrict__ Aagg,  // [M, KP] bf16
    const unsigned short* __restrict__ Axr,   // [M, KP] bf16
    const unsigned short* __restrict__ WT,    // [256, 2KP] bf16
    const float* __restrict__ bias,
    float* __restrict__ outf,                 // used if WF
    unsigned short* __restrict__ outb,        // used if WB
    int M)
{
    __shared__ __align__(16) unsigned short As[2 * 8192];   // 2 x [256][32]
    __shared__ __align__(16) unsigned short Bs[2 * 8192];   // 2 x [256][32]

    const int t   = threadIdx.x;
    const int l   = t & 63;
    const int wid = t >> 6;          // 0..15
    const int wr  = wid >> 2;        // 0..3
    const int wc  = wid & 3;         // 0..3
    const int m0  = blockIdx.x * 256;

    const int rin = l >> 2;                       // row within 16-row chunk
    const int csw = (l & 3) ^ ((l >> 3) & 3);     // swizzled source chunk

    // 32 chunks per K-tile (16 A + 16 B); this wave stages 2*wid, 2*wid+1
    const int sc0 = wid * 2, sc1 = sc0 + 1;

    constexpr int K2 = 2 * KP;
    constexpr int KT = K2 / 32;

    auto stageChunk = [&](int buf, int kt, int ch) {
        const int kb = kt * 32;
        if (ch < 16) {              // A chunk: rows m0+ch*16 .. +16
            const unsigned short* Asrc;
            int kk;
            if (kb < KP) { Asrc = Aagg; kk = kb; }
            else         { Asrc = Axr;  kk = kb - KP; }
            int row = m0 + ch * 16 + rin; if (row >= M) row = M - 1;
            gload16(Asrc + (size_t)row * KP + kk + csw * 8,
                    As + buf * 8192 + ch * 512);
        } else {                    // B chunk: WT rows (ch-16)*16 .. +16
            int row = (ch - 16) * 16 + rin;
            gload16(WT + (size_t)row * K2 + kb + csw * 8,
                    Bs + buf * 8192 + (ch - 16) * 512);
        }
    };
    auto stage = [&](int buf, int kt) {
        stageChunk(buf, kt, sc0);
        stageChunk(buf, kt, sc1);
    };

    // fragment-read offsets: row fr = l&15, logical chunk g = l>>4,
    // lds chunk = g ^ ((fr>>1)&3) = (l>>4) ^ ((l>>1)&3)
    const int fr  = l & 15;
    const int swz = ((l >> 4) ^ ((l >> 1) & 3)) * 8;    // ushort units
    const int aOff = (wr * 64 + fr) * 32 + swz;
    const int bOff = (wc * 64 + fr) * 32 + swz;

    f32x4 acc[4][4] = {};

    stage(0, 0);

    int cur = 0;
    for (int kt = 0; kt < KT; ++kt) {
        if (kt + 1 < KT) {
            stage(cur ^ 1, kt + 1);   // 1-deep prefetch (2 more loads)
            asm volatile("s_waitcnt vmcnt(2)" ::: "memory");   // tile kt landed
        } else {
            asm volatile("s_waitcnt vmcnt(0)" ::: "memory");
        }
        __builtin_amdgcn_s_barrier();            // raw: no auto drain
        __builtin_amdgcn_sched_barrier(0);

        const unsigned short* Ard = As + cur * 8192 + aOff;
        const unsigned short* Brd = Bs + cur * 8192 + bOff;
        short8 af[4], bf[4];
        #pragma unroll
        for (int i = 0; i < 4; ++i)
            af[i] = *reinterpret_cast<const short8*>(Ard + i * 512);
        #pragma unroll
        for (int i = 0; i < 4; ++i)
            bf[i] = *reinterpret_cast<const short8*>(Brd + i * 512);
        #pragma unroll
        for (int i = 0; i < 4; ++i)
            #pragma unroll
            for (int j = 0; j < 4; ++j)
                acc[i][j] = __builtin_amdgcn_mfma_f32_16x16x32_bf16(
                    af[i], bf[j], acc[i][j], 0, 0, 0);

        asm volatile("s_waitcnt lgkmcnt(0)" ::: "memory");  // reads done
        __builtin_amdgcn_s_barrier();            // safe to overwrite cur
        __builtin_amdgcn_sched_barrier(0);
        cur ^= 1;
    }

    // epilogue: C/D layout col = l&15, row = (l>>4)*4 + reg
    const int rq = (l >> 4) * 4;
    #pragma unroll
    for (int fn = 0; fn < 4; ++fn) {
        const int col = wc * 64 + fn * 16 + fr;
        const float bb = bias[col];
        #pragma unroll
        for (int fm = 0; fm < 4; ++fm) {
            const int rbase = m0 + wr * 64 + fm * 16 + rq;
            #pragma unroll
            for (int j = 0; j < 4; ++j) {
                const int r = rbase + j;
                if (r < M) {
                    float v = fmaxf(acc[fm][fn][j] + bb, 0.f);
                    if (WF) outf[(size_t)r * DHID + col] = v;
                    if (WB) outb[(size_t)r * DHID + col] = f2b(v);
                }
            }
        }
    }
}

extern "C" void kernel_launch(void* const* d_in, const int* in_sizes, int n_in,
                              void* d_out, int out_size, void* d_ws, size_t ws_size,
                              hipStream_t stream)
{
    const float* x   = (const float*)d_in[0];
    const int*   ei  = (const int*)d_in[1];
    const int*   src = ei;
    const int*   dst = ei + NE;
    const float* Wl0 = (const float*)d_in[2];
    const float* Wr0 = (const float*)d_in[3];
    const float* b0  = (const float*)d_in[4];
    const float* Wl1 = (const float*)d_in[5];
    const float* Wr1 = (const float*)d_in[6];
    const float* b1  = (const float*)d_in[7];
    float* out = (float*)d_out;

    // workspace layout (bytes):
    //   hist    : @0          400384
    //   offs    : @400384     400640
    //   perm    : @801024     2500352
    //   bsum    : @3301376    4096
    //   bpre    : @3305472    4096
    //   cursor  : @3309568    400384
    //   WT0     : @3709952    131072
    //   WT1     : @3841024    262144
    //   xb      : @4103168    25600000
    //   h0b     : @29703168   51200000
    //   aggb    : @80903168   51200000
    // total ~132.1 MB
    char* ws = (char*)d_ws;
    int*            hist   = (int*)(ws);
    int*            offs   = (int*)(ws + 400384);
    int*            perm   = (int*)(ws + 801024);
    int*            bsum   = (int*)(ws + 3301376);
    int*            bpre   = (int*)(ws + 3305472);
    int*            cursor = (int*)(ws + 3309568);
    unsigned short* WT0    = (unsigned short*)(ws + 3709952);
    unsigned short* WT1    = (unsigned short*)(ws + 3841024);
    unsigned short* xb     = (unsigned short*)(ws + 4103168);
    unsigned short* h0b    = (unsigned short*)(ws + 29703168);
    unsigned short* aggb   = (unsigned short*)(ws + 80903168);

    // prep (also zeroes hist), then CSR chain
    prep_all_kernel<<<CONV_BLKS + 256 + 512 + NB, 256, 0, stream>>>(
        x, xb, Wl0, Wr0, WT0, Wl1, Wr1, WT1, hist);
    hist_kernel<<<(NE + 255) / 256, 256, 0, stream>>>(dst, hist);
    chunk_sum_kernel<<<NB, 256, 0, stream>>>(hist, bsum);
    scan_bsum_kernel<<<1, 512, 0, stream>>>(bsum, bpre);
    scatter_offs_kernel<<<NB, 256, 0, stream>>>(hist, bpre, offs, cursor);
    perm_kernel<<<(NE + 255) / 256, 256, 0, stream>>>(src, dst, cursor, perm);

    constexpr int NWBLK = (NN * 64) / 256;     // 25000 exactly
    const int GEMM_BLKS = (NN + 255) / 256;    // 391 blocks, full N per block

    // ---- layer 0 ----
    gather_mean_kernel<DIN><<<NWBLK, 256, 0, stream>>>(offs, perm, xb, aggb);
    sage_mfma_gemm<DIN, false, true><<<GEMM_BLKS, 1024, 0, stream>>>(
        aggb, xb, WT0, b0, nullptr, h0b, NN);

    // ---- layer 1 ----
    gather_mean_kernel<DHID><<<NWBLK, 256, 0, stream>>>(offs, perm, h0b, aggb);
    sage_mfma_gemm<DHID, true, false><<<GEMM_BLKS, 1024, 0, stream>>>(
        aggb, h0b, WT1, b1, out, nullptr, NN);
}